// Round 6
// baseline (2467.899 us; speedup 1.0000x reference)
//
#include <hip/hip_runtime.h>

typedef __attribute__((ext_vector_type(8))) short short8;
typedef __attribute__((ext_vector_type(4))) float f32x4;
typedef unsigned short u16;

#define DEVI static __device__ __forceinline__

// BS=4 NQ=1024 D=256 NH=8 NP=4 L=6 DFF=1024 H=200 W=150 NV=30000 DH=32
// d_in/d_out are FP32. Internals: bf16 MFMA, fp32 accum, fp32 residual+LN.
DEVI float b2f(u16 u){ unsigned int x = ((unsigned int)u) << 16; float f; __builtin_memcpy(&f, &x, 4); return f; }
DEVI u16 f2b(float f){ unsigned int u; __builtin_memcpy(&u, &f, 4); u += 0x7fffu + ((u >> 16) & 1u); return (u16)(u >> 16); }
DEVI short8 cvt8(const float* __restrict__ p){
  f32x4 a = *(const f32x4*)p;
  f32x4 b = *(const f32x4*)(p + 4);
  short8 r;
  r[0]=(short)f2b(a[0]); r[1]=(short)f2b(a[1]); r[2]=(short)f2b(a[2]); r[3]=(short)f2b(a[3]);
  r[4]=(short)f2b(b[0]); r[5]=(short)f2b(b[1]); r[6]=(short)f2b(b[2]); r[7]=(short)f2b(b[3]);
  return r;
}

// ---------------------------------------------------------------------------
// One-shot convert/pack of ALL fp32 params -> bf16 (plus obc fp32 pack).
// Unit = 8 elements. Segment sizes in units; see launcher for grid math.
// ---------------------------------------------------------------------------
__global__ __launch_bounds__(256) void cvtall_k(
    const float* __restrict__ sa_in_w, const float* __restrict__ sa_out_w,
    const float* __restrict__ val_w,   const float* __restrict__ cout_w,
    const float* __restrict__ ff1w,    const float* __restrict__ ff2w,
    const float* __restrict__ off_w,   const float* __restrict__ aw_w,
    const float* __restrict__ off_b,   const float* __restrict__ aw_b,
    const float* __restrict__ src,
    u16* __restrict__ wsa_b, u16* __restrict__ wsao_b, u16* __restrict__ wval_b,
    u16* __restrict__ wcao_b, u16* __restrict__ wff1_b, u16* __restrict__ wff2_b,
    u16* __restrict__ wofaw, float* __restrict__ obc, u16* __restrict__ src_b)
{
  long u = (long)blockIdx.x * 256 + threadIdx.x;
  if (u < 147456) { ((short8*)wsa_b)[u]  = cvt8(sa_in_w  + u * 8); return; } u -= 147456;
  if (u < 49152)  { ((short8*)wsao_b)[u] = cvt8(sa_out_w + u * 8); return; } u -= 49152;
  if (u < 49152)  { ((short8*)wval_b)[u] = cvt8(val_w    + u * 8); return; } u -= 49152;
  if (u < 49152)  { ((short8*)wcao_b)[u] = cvt8(cout_w   + u * 8); return; } u -= 49152;
  if (u < 196608) { ((short8*)wff1_b)[u] = cvt8(ff1w     + u * 8); return; } u -= 196608;
  if (u < 196608) { ((short8*)wff2_b)[u] = cvt8(ff2w     + u * 8); return; } u -= 196608;
  if (u < 12288)  { long e = u * 8; int l = (int)(e >> 14); long rem = e & 16383;
                    ((short8*)wofaw)[(l * 24576 + rem) >> 3] = cvt8(off_w + e); return; } u -= 12288;
  if (u < 6144)   { long e = u * 8; int l = (int)(e >> 13); long rem = e & 8191;
                    ((short8*)wofaw)[(l * 24576 + 16384 + rem) >> 3] = cvt8(aw_w + e); return; } u -= 6144;
  if (u < 3840000){ ((short8*)src_b)[u]  = cvt8(src + u * 8); return; } u -= 3840000;
  if (u < 72) {
    long e0 = u * 8;
#pragma unroll
    for (int j = 0; j < 8; j++) {
      long e = e0 + j;
      if (e < 384) { int l = (int)(e >> 6); obc[l * 96 + (e & 63)] = off_b[e]; }
      else { long e2 = e - 384; int l = (int)(e2 >> 5); obc[l * 96 + 64 + (e2 & 31)] = aw_b[e2]; }
    }
  }
}

// ---------------------------------------------------------------------------
// vproj6_k: value projection for ALL 6 layers, layer loop inside the block.
// Round-2-proven structure (As staged once via global_load_lds; Cs-transposed
// full-line store epilogue; traffic exact: FETCH 42MB, WRITE 360MB) with Cs
// shrunk 32KB -> 8KB, drained in 4 chunks/layer. LDS = 40KB -> 4 blocks/CU
// (was 2), doubling in-flight write capacity (round-2 diagnosis: writes
// latency-bound by occupancy at ~1.5 TB/s). NO launch_bounds min-waves:
// rounds 4/5 proved forcing it caps VGPR at 64 -> accumulator spills to
// scratch (VGPR_Count=64 + GB-scale FETCH/WRITE = the spill signature).
// ---------------------------------------------------------------------------
__global__ __launch_bounds__(256) void vproj6_k(
    const u16* __restrict__ A,       // src_b, lda = 256
    const u16* __restrict__ W,       // wval_b, 65536 elems per layer
    const float* __restrict__ bias,  // val_b, 256 per layer
    u16* __restrict__ C)             // vsrc, 30720000 elems per layer
{
  __shared__ u16 As[64 * 256];
  __shared__ u16 Cs[16 * 256];
  const int wave = threadIdx.x >> 6, lane = threadIdx.x & 63;
  const int bm = blockIdx.x * 64;
  const int bn = wave * 64;
  const int lr = lane & 15, lq = lane >> 4;
  // stage A once: 64 rows x 256 k, 16B per lane per iter, linear LDS dest
#pragma unroll
  for (int it = 0; it < 8; it++) {
    int ub = wave * 512 + it * 64;
    int u = ub + lane;
    int row = u & 63, kgrp = u >> 6;
    const u16* ga = A + (long)(bm + row) * 256 + kgrp * 8;
    __builtin_amdgcn_global_load_lds(
        (const __attribute__((address_space(1))) void*)ga,
        (__attribute__((address_space(3))) void*)(As + ub * 8), 16, 0, 0);
  }
  __syncthreads();
#pragma unroll 1
  for (int l = 0; l < 6; l++) {
    const u16* Wz = W + (long)l * 65536;
    f32x4 acc[4][4] = {};
#pragma unroll
    for (int s = 0; s < 8; s++) {
      short8 af[4], bf[4];
#pragma unroll
      for (int i = 0; i < 4; i++)
        af[i] = *(const short8*)(As + ((s * 4 + lq) * 64 + i * 16 + lr) * 8);
#pragma unroll
      for (int j = 0; j < 4; j++)
        bf[j] = *(const short8*)(Wz + (long)(bn + j * 16 + lr) * 256 + s * 32 + lq * 8);
#pragma unroll
      for (int i = 0; i < 4; i++)
#pragma unroll
        for (int j = 0; j < 4; j++)
          acc[i][j] = __builtin_amdgcn_mfma_f32_16x16x32_bf16(af[i], bf[j], acc[i][j], 0, 0, 0);
    }
    const float* bz = bias + l * 256;
    u16* Cl = C + (long)l * 30720000 + (long)bm * 256;
    // drain the 64x256 tile through an 8KB Cs in 4 chunks of 16 rows
#pragma unroll 1
    for (int i = 0; i < 4; i++) {
      __syncthreads();   // previous chunk's read-back complete
      // scatter: 32B-slot XOR swizzle; lq = rowl>>2 -> 4 disjoint 8-bank sets
#pragma unroll
      for (int j = 0; j < 4; j++) {
        int colt = bn + j * 16 + lr;
        float bv = bz[colt];
#pragma unroll
        for (int r = 0; r < 4; r++) {
          int rowl = lq * 4 + r;
          int byte = (rowl << 9) + (colt << 1);
          byte ^= ((rowl >> 2) & 3) << 5;
          *(u16*)((char*)Cs + byte) = f2b(acc[i][j][r] + bv);
        }
      }
      __syncthreads();
      // linear read-back + contiguous stores: 1KB per wave-op, full lines
#pragma unroll
      for (int t = 0; t < 2; t++) {
        int idx = t * 256 + threadIdx.x;
        int byte = idx << 4;
        byte ^= ((byte >> 11) & 3) << 5;  // rowl bits 2-3 = byte bits 11-12
        short8 v = *(const short8*)((const char*)Cs + byte);
        ((short8*)(Cl + (long)i * 4096))[idx] = v;
      }
    }
  }
}

// ---------------------------------------------------------------------------
// gemm_w_k<MT>: MT(M) x 256(N) block; 4 waves side-by-side (wave = 64 cols).
// A chunk (MT x 256) staged in LDS via global_load_lds(16B); W streamed (L2).
// z-batched via wZ/bZ/cZ strides. Optional RELU / bf16-out / fused V^T /
// fused residual+LayerNorm epilogue. Grid must exactly cover M (grid.x*MT)
// and N (grid.y*256); K % 256 == 0.
// ---------------------------------------------------------------------------
template<int MT, bool RELU, bool OUTBF, bool VT, bool LN>
__global__ __launch_bounds__(256) void gemm_w_k(
    const u16* __restrict__ A, int lda,
    const u16* __restrict__ W, long wZ,
    const float* __restrict__ bias, int bZ,
    void* __restrict__ Cv, int ldo, long cZ,
    int K,
    u16* __restrict__ vt,
    const float* __restrict__ res,
    const float* __restrict__ lnw, const float* __restrict__ lnb,
    const float* __restrict__ qpos,
    float* __restrict__ out_f, u16* __restrict__ out_b16,
    u16* __restrict__ qk_b16, float* __restrict__ hsp)
{
  __shared__ u16 As[32 * MT * 8];
  __shared__ float r1s[4][64], r2s[4][64], mArr[64], iArr[64];
  const int wave = threadIdx.x >> 6, lane = threadIdx.x & 63;
  const int bm = blockIdx.x * MT;
  const int bn = blockIdx.y * 256 + wave * 64;
  const int lr = lane & 15, lq = lane >> 4;
  constexpr int SH = (MT == 64) ? 6 : 5;
  const u16* Wz = W + (long)blockIdx.z * wZ;
  const float* bz = bias + (long)blockIdx.z * bZ;
  f32x4 acc[MT / 16][4] = {};
  const int nchunks = K >> 8;
  for (int ch = 0; ch < nchunks; ch++) {
#pragma unroll
    for (int it = 0; it < MT / 8; it++) {
      int ub = wave * (MT * 8) + it * 64;
      int u = ub + lane;
      int row = u & (MT - 1), kgrp = u >> SH;
      const u16* ga = A + (long)(bm + row) * lda + ch * 256 + kgrp * 8;
      __builtin_amdgcn_global_load_lds(
          (const __attribute__((address_space(1))) void*)ga,
          (__attribute__((address_space(3))) void*)(As + ub * 8), 16, 0, 0);
    }
    __syncthreads();
#pragma unroll
    for (int s = 0; s < 8; s++) {
      short8 af[MT / 16], bf[4];
#pragma unroll
      for (int i = 0; i < MT / 16; i++)
        af[i] = *(const short8*)(As + ((s * 4 + lq) * MT + i * 16 + lr) * 8);
#pragma unroll
      for (int j = 0; j < 4; j++) {
        int cc = bn + j * 16 + lr;
        bf[j] = *(const short8*)(Wz + (long)cc * K + ch * 256 + s * 32 + lq * 8);
      }
#pragma unroll
      for (int i = 0; i < MT / 16; i++)
#pragma unroll
        for (int j = 0; j < 4; j++)
          acc[i][j] = __builtin_amdgcn_mfma_f32_16x16x32_bf16(af[i], bf[j], acc[i][j], 0, 0, 0);
    }
    __syncthreads();
  }

  float bv[4];
#pragma unroll
  for (int j = 0; j < 4; j++) bv[j] = bz[bn + j * 16 + lr];

  if (!LN) {
    char* Cz = (char*)Cv;
#pragma unroll
    for (int j = 0; j < 4; j++) {
      int cc = bn + j * 16 + lr;
#pragma unroll
      for (int i = 0; i < MT / 16; i++) {
#pragma unroll
        for (int r = 0; r < 4; r++) {
          int rr = bm + i * 16 + lq * 4 + r;
          float v = acc[i][j][r] + bv[j];
          if (RELU) v = fmaxf(v, 0.f);
          long idx = (long)blockIdx.z * cZ + (long)rr * ldo + cc;
          if (OUTBF) ((u16*)Cz)[idx] = f2b(v);
          else       ((float*)Cz)[idx] = v;
          if (VT) {
            int b_ = rr >> 10, q_ = rr & 1023, h_ = cc >> 5, dh_ = cc & 31;
            vt[(long)((((b_ << 3) + h_) << 5) + dh_) * 1024 + q_] = f2b(v);
          }
        }
      }
    }
  } else {
    float s1[MT / 16][4] = {}, s2[MT / 16][4] = {};
#pragma unroll
    for (int i = 0; i < MT / 16; i++) {
#pragma unroll
      for (int r = 0; r < 4; r++) {
        int rowg = bm + i * 16 + lq * 4 + r;
#pragma unroll
        for (int j = 0; j < 4; j++) {
          int cc = bn + j * 16 + lr;
          float x = acc[i][j][r] + bv[j] + res[(long)rowg * 256 + cc];
          s1[i][r] += x; s2[i][r] += x * x;
        }
      }
    }
#pragma unroll
    for (int i = 0; i < MT / 16; i++)
#pragma unroll
      for (int r = 0; r < 4; r++) {
#pragma unroll
        for (int m = 1; m <= 8; m <<= 1) {
          s1[i][r] += __shfl_xor(s1[i][r], m);
          s2[i][r] += __shfl_xor(s2[i][r], m);
        }
      }
    if (lr == 0) {
#pragma unroll
      for (int i = 0; i < MT / 16; i++)
#pragma unroll
        for (int r = 0; r < 4; r++) {
          int rl = i * 16 + lq * 4 + r;
          r1s[wave][rl] = s1[i][r];
          r2s[wave][rl] = s2[i][r];
        }
    }
    __syncthreads();
    if (threadIdx.x < MT) {
      int t = threadIdx.x;
      float a = r1s[0][t] + r1s[1][t] + r1s[2][t] + r1s[3][t];
      float b = r2s[0][t] + r2s[1][t] + r2s[2][t] + r2s[3][t];
      float m = a * (1.f / 256.f);
      float var = b * (1.f / 256.f) - m * m;
      mArr[t] = m;
      iArr[t] = rsqrtf(var + 1e-5f);
    }
    __syncthreads();
#pragma unroll
    for (int i = 0; i < MT / 16; i++) {
#pragma unroll
      for (int r = 0; r < 4; r++) {
        int rl = i * 16 + lq * 4 + r;
        int rowg = bm + rl;
        float m = mArr[rl], inv = iArr[rl];
#pragma unroll
        for (int j = 0; j < 4; j++) {
          int cc = bn + j * 16 + lr;
          long idx = (long)rowg * 256 + cc;
          float x = acc[i][j][r] + bv[j] + res[idx];
          float y = (x - m) * inv * lnw[cc] + lnb[cc];
          out_f[idx] = y;
          if (out_b16) out_b16[idx] = f2b(y);
          if (qk_b16)  qk_b16[idx]  = f2b(y + qpos[idx]);
          if (hsp)     hsp[idx]     = y;
        }
      }
    }
  }
}

// ---------------------------------------------------------------------------
// qkv_k: merged Q/K/V projection. grid (64, 3): y=0 -> Q cols of qkbuf,
// y=1 -> K cols, y=2 -> V (writes vt only). MT=64 core identical to gemm_w_k.
// ---------------------------------------------------------------------------
__global__ __launch_bounds__(256) void qkv_k(
    const u16* __restrict__ qk_b, const u16* __restrict__ out_b,
    const u16* __restrict__ wsa, const float* __restrict__ bsa,
    u16* __restrict__ qkbuf, u16* __restrict__ vt)
{
  __shared__ u16 As[32 * 64 * 8];
  const int sel = blockIdx.y;
  const u16* A = (sel == 2) ? out_b : qk_b;
  const u16* W = wsa + (long)sel * 256 * 256;
  const int wave = threadIdx.x >> 6, lane = threadIdx.x & 63;
  const int bm = blockIdx.x * 64;
  const int bn = wave * 64;
  const int lr = lane & 15, lq = lane >> 4;
  f32x4 acc[4][4] = {};
#pragma unroll
  for (int it = 0; it < 8; it++) {
    int ub = wave * 512 + it * 64;
    int u = ub + lane;
    int row = u & 63, kgrp = u >> 6;
    const u16* ga = A + (long)(bm + row) * 256 + kgrp * 8;
    __builtin_amdgcn_global_load_lds(
        (const __attribute__((address_space(1))) void*)ga,
        (__attribute__((address_space(3))) void*)(As + ub * 8), 16, 0, 0);
  }
  __syncthreads();
#pragma unroll
  for (int s = 0; s < 8; s++) {
    short8 af[4], bf[4];
#pragma unroll
    for (int i = 0; i < 4; i++)
      af[i] = *(const short8*)(As + ((s * 4 + lq) * 64 + i * 16 + lr) * 8);
#pragma unroll
    for (int j = 0; j < 4; j++) {
      int cc = bn + j * 16 + lr;
      bf[j] = *(const short8*)(W + (long)cc * 256 + s * 32 + lq * 8);
    }
#pragma unroll
    for (int i = 0; i < 4; i++)
#pragma unroll
      for (int j = 0; j < 4; j++)
        acc[i][j] = __builtin_amdgcn_mfma_f32_16x16x32_bf16(af[i], bf[j], acc[i][j], 0, 0, 0);
  }
  float bv[4];
#pragma unroll
  for (int j = 0; j < 4; j++) bv[j] = bsa[sel * 256 + bn + j * 16 + lr];
#pragma unroll
  for (int j = 0; j < 4; j++) {
    int cc = bn + j * 16 + lr;
#pragma unroll
    for (int i = 0; i < 4; i++) {
#pragma unroll
      for (int r = 0; r < 4; r++) {
        int rr = bm + i * 16 + lq * 4 + r;
        float v = acc[i][j][r] + bv[j];
        if (sel < 2) {
          qkbuf[(long)rr * 512 + sel * 256 + cc] = f2b(v);
        } else {
          int b_ = rr >> 10, q_ = rr & 1023, h_ = cc >> 5, dh_ = cc & 31;
          vt[(long)((((b_ << 3) + h_) << 5) + dh_) * 1024 + q_] = f2b(v);
        }
      }
    }
  }
}

// ---------------------------------------------------------------------------
// Flash self-attention (round-6 proven): block per (b,h,q-tile 128).
// ---------------------------------------------------------------------------
__global__ __launch_bounds__(256) void flash_k(
    const u16* __restrict__ qkbuf, const u16* __restrict__ vt,
    u16* __restrict__ obuf)
{
  const float SC = 0.17677669529663687f;
  __shared__ u16 Plds[4][32][136];
  const int bh = blockIdx.x >> 3;
  const int b = bh >> 3, h = bh & 7;
  const int qt = blockIdx.x & 7;
  const int wave = threadIdx.x >> 6, lane = threadIdx.x & 63;
  const int lr = lane & 15, lq = lane >> 4;
  const int qbase = qt * 128 + wave * 32;

  short8 qf[2];
#pragma unroll
  for (int i = 0; i < 2; i++)
    qf[i] = *(const short8*)(qkbuf + (long)(b * 1024 + qbase + i * 16 + lr) * 512 + h * 32 + lq * 8);

  const u16* Kb = qkbuf + (long)b * 1024 * 512 + 256 + h * 32;
  const u16* Vb = vt + (long)bh * 32 * 1024;

  f32x4 acc_o[2][2] = {};
  float m_run[2][4], l_run[2][4];
#pragma unroll
  for (int i = 0; i < 2; i++)
#pragma unroll
    for (int r = 0; r < 4; r++){ m_run[i][r] = -3e38f; l_run[i][r] = 0.f; }

  for (int kt = 0; kt < 8; kt++) {
    f32x4 s[2][8] = {};
#pragma unroll
    for (int j = 0; j < 8; j++) {
      short8 kf = *(const short8*)(Kb + (long)(kt * 128 + j * 16 + lr) * 512 + lq * 8);
#pragma unroll
      for (int i = 0; i < 2; i++)
        s[i][j] = __builtin_amdgcn_mfma_f32_16x16x32_bf16(qf[i], kf, s[i][j], 0, 0, 0);
    }
#pragma unroll
    for (int i = 0; i < 2; i++) {
#pragma unroll
      for (int r = 0; r < 4; r++) {
        float mx = s[i][0][r];
#pragma unroll
        for (int j = 1; j < 8; j++) mx = fmaxf(mx, s[i][j][r]);
#pragma unroll
        for (int m = 1; m <= 8; m <<= 1) mx = fmaxf(mx, __shfl_xor(mx, m));
        float m_new = fmaxf(m_run[i][r], mx);
        float alpha = __expf((m_run[i][r] - m_new) * SC);
        float sum = 0.f;
        int row = i * 16 + lq * 4 + r;
#pragma unroll
        for (int j = 0; j < 8; j++) {
          float p = __expf((s[i][j][r] - m_new) * SC);
          sum += p;
          Plds[wave][row][j * 16 + lr] = f2b(p);
        }
#pragma unroll
        for (int m = 1; m <= 8; m <<= 1) sum += __shfl_xor(sum, m);
        l_run[i][r] = l_run[i][r] * alpha + sum;
        m_run[i][r] = m_new;
#pragma unroll
        for (int d = 0; d < 2; d++) acc_o[i][d][r] *= alpha;
      }
    }
#pragma unroll
    for (int kc = 0; kc < 4; kc++) {
      short8 pf[2];
#pragma unroll
      for (int i = 0; i < 2; i++)
        pf[i] = *(const short8*)&Plds[wave][i * 16 + lr][kc * 32 + lq * 8];
#pragma unroll
      for (int d = 0; d < 2; d++) {
        short8 vf = *(const short8*)(Vb + (long)(d * 16 + lr) * 1024 + kt * 128 + kc * 32 + lq * 8);
#pragma unroll
        for (int i = 0; i < 2; i++)
          acc_o[i][d] = __builtin_amdgcn_mfma_f32_16x16x32_bf16(pf[i], vf, acc_o[i][d], 0, 0, 0);
      }
    }
  }
#pragma unroll
  for (int i = 0; i < 2; i++) {
#pragma unroll
    for (int r = 0; r < 4; r++) {
      float inv = 1.f / l_run[i][r];
      int q = qbase + i * 16 + lq * 4 + r;
#pragma unroll
      for (int d = 0; d < 2; d++)
        obuf[(long)(b * 1024 + q) * 256 + h * 32 + d * 16 + lr] = f2b(acc_o[i][d][r] * inv);
    }
  }
}

// ---------------------------------------------------------------------------
// gemm64_k (bf16-only): 64x64 block, direct loads. Used for offaw (N=96).
// ---------------------------------------------------------------------------
__global__ __launch_bounds__(256) void gemm64_k(
    const u16* __restrict__ A, int lda,
    const u16* __restrict__ W, int ldw,
    const float* __restrict__ bias,
    float* __restrict__ C, int ldo,
    int M, int N, int K)
{
  const int wave = threadIdx.x >> 6, lane = threadIdx.x & 63;
  const int wm = wave >> 1, wn = wave & 1;
  const int bm = blockIdx.x * 64 + wm * 32;
  const int bn = blockIdx.y * 64 + wn * 32;
  const int lr = lane & 15, lq = lane >> 4;
  const int koff = lq * 8;
  f32x4 acc[2][2] = {};
  const short8 Z8 = {0,0,0,0,0,0,0,0};
  for (int k0 = 0; k0 < K; k0 += 32) {
    short8 af[2], bf[2];
#pragma unroll
    for (int i = 0; i < 2; i++) {
      int r = bm + i * 16 + lr;
      af[i] = (r < M) ? *(const short8*)(A + (long)r * lda + k0 + koff) : Z8;
    }
#pragma unroll
    for (int j = 0; j < 2; j++) {
      int c = bn + j * 16 + lr;
      bf[j] = (c < N) ? *(const short8*)(W + (long)c * ldw + k0 + koff) : Z8;
    }
#pragma unroll
    for (int i = 0; i < 2; i++)
#pragma unroll
      for (int j = 0; j < 2; j++)
        acc[i][j] = __builtin_amdgcn_mfma_f32_16x16x32_bf16(af[i], bf[j], acc[i][j], 0, 0, 0);
  }
#pragma unroll
  for (int j = 0; j < 2; j++) {
    int cc = bn + j * 16 + lr;
    if (cc >= N) continue;
    float bv = bias[cc];
#pragma unroll
    for (int i = 0; i < 2; i++) {
#pragma unroll
      for (int r = 0; r < 4; r++) {
        int rr = bm + i * 16 + lq * 4 + r;
        if (rr >= M) continue;
        C[(long)rr * ldo + cc] = acc[i][j][r] + bv;
      }
    }
  }
}

__global__ __launch_bounds__(256) void init_prep_k(const float* __restrict__ q, const float* __restrict__ qpos,
                                                   float* __restrict__ out_f, u16* __restrict__ out_b,
                                                   u16* __restrict__ qk_b){
  long i = (long)blockIdx.x * 256 + threadIdx.x;
  float o = q[i];
  out_f[i] = o;
  out_b[i] = f2b(o);
  qk_b[i]  = f2b(o + qpos[i]);
}

__global__ __launch_bounds__(256) void msda_k(
    const float* __restrict__ refp,
    const float* __restrict__ off, int ldoff,
    const float* __restrict__ aw, int ldaw,
    const u16* __restrict__ v,
    u16* __restrict__ o,
    long vstride)
{
  int tid = blockIdx.x * 256 + threadIdx.x;
  int dh = tid & 31;
  int h  = (tid >> 5) & 7;
  int bq = tid >> 8;
  int b  = bq >> 10;
  float rx = refp[bq * 2 + 0];
  float ry = refp[bq * 2 + 1];
  const float* offp = off + (long)bq * ldoff + h * 8;
  const float* awp  = aw  + (long)bq * ldaw + h * 4;
  float a0 = awp[0], a1 = awp[1], a2 = awp[2], a3 = awp[3];
  float am = fmaxf(fmaxf(a0, a1), fmaxf(a2, a3));
  float e[4];
  e[0] = __expf(a0 - am); e[1] = __expf(a1 - am); e[2] = __expf(a2 - am); e[3] = __expf(a3 - am);
  float einv = 1.f / (e[0] + e[1] + e[2] + e[3]);
  const u16* vb = v + b * vstride + h * 32 + dh;
  float accv = 0.f;
#pragma unroll
  for (int pp = 0; pp < 4; pp++){
    float x = rx * 150.f + offp[pp * 2 + 0] - 0.5f;
    float y = ry * 200.f + offp[pp * 2 + 1] - 0.5f;
    float x0 = floorf(x), y0 = floorf(y);
    float s = 0.f;
#pragma unroll
    for (int c = 0; c < 4; c++){
      int dx = c & 1, dy = c >> 1;
      float xi = x0 + dx, yi = y0 + dy;
      float wt = (1.f - fabsf(x - xi)) * (1.f - fabsf(y - yi));
      if (xi >= 0.f && xi < 150.f && yi >= 0.f && yi < 200.f && wt > 0.f) {
        int xc = (int)xi, yc = (int)yi;
        s += wt * b2f(vb[((long)yc * 150 + xc) * 256]);
      }
    }
    accv += e[pp] * einv * s;
  }
  o[(long)bq * 256 + h * 32 + dh] = f2b(accv);
}

__global__ __launch_bounds__(256) void refs_k(const float* __restrict__ r, float* __restrict__ dst){
  int i = blockIdx.x * 256 + threadIdx.x;
  dst[i] = r[i & 8191];
}

// ---------------------------------------------------------------------------
extern "C" void kernel_launch(void* const* d_in, const int* in_sizes, int n_in,
                              void* d_out, int out_size, void* d_ws, size_t ws_size,
                              hipStream_t stream)
{
  (void)in_sizes; (void)n_in; (void)out_size;
  const float* query = (const float*)d_in[0];
  const float* qpos  = (const float*)d_in[1];
  const float* refp  = (const float*)d_in[2];
  const float* src   = (const float*)d_in[3];
  const float* sa_in_w  = (const float*)d_in[6];
  const float* sa_in_b  = (const float*)d_in[7];
  const float* sa_out_w = (const float*)d_in[8];
  const float* sa_out_b = (const float*)d_in[9];
  const float* off_w = (const float*)d_in[10];
  const float* off_b = (const float*)d_in[11];
  const float* aw_w  = (const float*)d_in[12];
  const float* aw_b  = (const float*)d_in[13];
  const float* val_w = (const float*)d_in[14];
  const float* val_b = (const float*)d_in[15];
  const float* cout_w = (const float*)d_in[16];
  const float* cout_b = (const float*)d_in[17];
  const float* n1w = (const float*)d_in[18]; const float* n1b = (const float*)d_in[19];
  const float* n2w = (const float*)d_in[20]; const float* n2b = (const float*)d_in[21];
  const float* n3w = (const float*)d_in[22]; const float* n3b = (const float*)d_in[23];
  const float* ff1w = (const float*)d_in[24]; const float* ff1b = (const float*)d_in[25];
  const float* ff2w = (const float*)d_in[26]; const float* ff2b = (const float*)d_in[27];

  float* hs = (float*)d_out;
  float* refs_out = hs + (long)6 * 4096 * 256;

  char* p = (char*)d_ws;
  auto alloc = [&](size_t bytes){ char* r = p; p += (bytes + 255) & ~(size_t)255; return r; };
  float* out_f = (float*)alloc(4194304);
  u16*   qk_b  = (u16*)  alloc(2097152);
  u16*   out_b = (u16*)  alloc(2097152);
  u16* wsa_b  = (u16*)alloc(2359296);
  u16* wsao_b = (u16*)alloc(786432);
  u16* wofaw  = (u16*)alloc(294912);
  u16* wval_b = (u16*)alloc(786432);
  u16* wcao_b = (u16*)alloc(786432);
  u16* wff1_b = (u16*)alloc(3145728);
  u16* wff2_b = (u16*)alloc(3145728);
  float* obc  = (float*)alloc(2304);
  u16* src_b  = (u16*)alloc(61440000);
  u16* qkbuf  = (u16*)alloc(4194304);
  u16* vt     = (u16*)alloc(2097152);
  u16* obuf   = (u16*)alloc(2097152);
  float* oawo = (float*)alloc(1572864);
  u16* mo     = (u16*)alloc(2097152);
  u16* ffh    = (u16*)alloc(8388608);
  size_t used = (size_t)(p - (char*)d_ws);
  const bool big = (ws_size >= used + 368640000ull);   // room for 6-layer vsrc
  u16* vsrc = (u16*)alloc(big ? 368640000ull : 61440000ull);

  init_prep_k<<<4096, 256, 0, stream>>>(query, qpos, out_f, out_b, qk_b);
  cvtall_k<<<17761, 256, 0, stream>>>(sa_in_w, sa_out_w, val_w, cout_w, ff1w, ff2w,
                                      off_w, aw_w, off_b, aw_b, src,
                                      wsa_b, wsao_b, wval_b, wcao_b, wff1_b, wff2_b,
                                      wofaw, obc, src_b);
  if (big) {
    // all 6 layers' value projections in one launch, layer loop INSIDE the
    // block: A-tile staged once, 8KB-chunked Cs transposed store epilogue.
    vproj6_k<<<1875, 256, 0, stream>>>(src_b, wval_b, val_b, vsrc);
  }

  for (int l = 0; l < 6; l++){
    const u16* wsa = wsa_b + (long)l * 768 * 256;
    // ---- self attention (flash) ----
    qkv_k<<<dim3(64,3,1),256,0,stream>>>(qk_b, out_b, wsa, sa_in_b + l * 768, qkbuf, vt);
    flash_k<<<256,256,0,stream>>>(qkbuf, vt, obuf);
    gemm_w_k<32,false,false,false,true><<<dim3(128,1,1),256,0,stream>>>(   // out-proj + norm2
        obuf, 256, wsao_b + (long)l*65536, 0, sa_out_b + l*256, 0, nullptr, 0, 0, 256,
        nullptr, out_f, n2w + l*256, n2b + l*256, qpos, out_f, nullptr, qk_b, nullptr);
    // ---- deformable cross attention ----
    gemm64_k<<<dim3(64,2,1),256,0,stream>>>(qk_b, 256, wofaw + (long)l*24576, 256,
        obc + l*96, oawo, 96, 4096, 96, 256);
    if (!big) {
      gemm_w_k<64,false,true,false,false><<<dim3(1875,1,1),256,0,stream>>>(
          src_b, 256, wval_b + (long)l*65536, 0, val_b + l*256, 0, vsrc, 256, 0, 256,
          nullptr, nullptr,nullptr,nullptr,nullptr,nullptr,nullptr,nullptr,nullptr);
    }
    const u16* vsl = big ? (vsrc + (long)l*30720000) : vsrc;
    msda_k<<<4096,256,0,stream>>>(refp, oawo, 96, oawo + 64, 96, vsl, mo, 7680000);
    gemm_w_k<32,false,false,false,true><<<dim3(128,1,1),256,0,stream>>>(   // ca-out + norm1
        mo, 256, wcao_b + (long)l*65536, 0, cout_b + l*256, 0, nullptr, 0, 0, 256,
        nullptr, out_f, n1w + l*256, n1b + l*256, nullptr, out_f, out_b, nullptr, nullptr);
    // ---- ffn ----
    gemm_w_k<64,true,true,false,false><<<dim3(64,4,1),256,0,stream>>>(     // ff1 + relu
        out_b, 256, wff1_b + (long)l*262144, 0, ff1b + l*1024, 0, ffh, 1024, 0, 256,
        nullptr, nullptr,nullptr,nullptr,nullptr,nullptr,nullptr,nullptr,nullptr);
    gemm_w_k<32,false,false,false,true><<<dim3(128,1,1),256,0,stream>>>(   // ff2 + norm3
        ffh, 1024, wff2_b + (long)l*262144, 0, ff2b + l*256, 0, nullptr, 0, 0, 1024,
        nullptr, out_f, n3w + l*256, n3b + l*256, qpos, out_f, out_b, qk_b,
        hs + (long)l*1048576);
  }
  refs_k<<<192,256,0,stream>>>(refp, refs_out);
}

// Round 7
// 1678.589 us; speedup vs baseline: 1.4702x; 1.4702x over previous
//
#include <hip/hip_runtime.h>

typedef __attribute__((ext_vector_type(8))) short short8;
typedef __attribute__((ext_vector_type(4))) float f32x4;
typedef unsigned short u16;

#define DEVI static __device__ __forceinline__

// BS=4 NQ=1024 D=256 NH=8 NP=4 L=6 DFF=1024 H=200 W=150 NV=30000 DH=32
// d_in/d_out are FP32. Internals: bf16 MFMA, fp32 accum, fp32 residual+LN.
DEVI float b2f(u16 u){ unsigned int x = ((unsigned int)u) << 16; float f; __builtin_memcpy(&f, &x, 4); return f; }
DEVI u16 f2b(float f){ unsigned int u; __builtin_memcpy(&u, &f, 4); u += 0x7fffu + ((u >> 16) & 1u); return (u16)(u >> 16); }
DEVI short8 cvt8(const float* __restrict__ p){
  f32x4 a = *(const f32x4*)p;
  f32x4 b = *(const f32x4*)(p + 4);
  short8 r;
  r[0]=(short)f2b(a[0]); r[1]=(short)f2b(a[1]); r[2]=(short)f2b(a[2]); r[3]=(short)f2b(a[3]);
  r[4]=(short)f2b(b[0]); r[5]=(short)f2b(b[1]); r[6]=(short)f2b(b[2]); r[7]=(short)f2b(b[3]);
  return r;
}

// ---------------------------------------------------------------------------
// One-shot convert/pack of ALL fp32 params -> bf16 (plus obc fp32 pack).
// Unit = 8 elements. Segment sizes in units; see launcher for grid math.
// ---------------------------------------------------------------------------
__global__ __launch_bounds__(256) void cvtall_k(
    const float* __restrict__ sa_in_w, const float* __restrict__ sa_out_w,
    const float* __restrict__ val_w,   const float* __restrict__ cout_w,
    const float* __restrict__ ff1w,    const float* __restrict__ ff2w,
    const float* __restrict__ off_w,   const float* __restrict__ aw_w,
    const float* __restrict__ off_b,   const float* __restrict__ aw_b,
    const float* __restrict__ src,
    u16* __restrict__ wsa_b, u16* __restrict__ wsao_b, u16* __restrict__ wval_b,
    u16* __restrict__ wcao_b, u16* __restrict__ wff1_b, u16* __restrict__ wff2_b,
    u16* __restrict__ wofaw, float* __restrict__ obc, u16* __restrict__ src_b)
{
  long u = (long)blockIdx.x * 256 + threadIdx.x;
  if (u < 147456) { ((short8*)wsa_b)[u]  = cvt8(sa_in_w  + u * 8); return; } u -= 147456;
  if (u < 49152)  { ((short8*)wsao_b)[u] = cvt8(sa_out_w + u * 8); return; } u -= 49152;
  if (u < 49152)  { ((short8*)wval_b)[u] = cvt8(val_w    + u * 8); return; } u -= 49152;
  if (u < 49152)  { ((short8*)wcao_b)[u] = cvt8(cout_w   + u * 8); return; } u -= 49152;
  if (u < 196608) { ((short8*)wff1_b)[u] = cvt8(ff1w     + u * 8); return; } u -= 196608;
  if (u < 196608) { ((short8*)wff2_b)[u] = cvt8(ff2w     + u * 8); return; } u -= 196608;
  if (u < 12288)  { long e = u * 8; int l = (int)(e >> 14); long rem = e & 16383;
                    ((short8*)wofaw)[(l * 24576 + rem) >> 3] = cvt8(off_w + e); return; } u -= 12288;
  if (u < 6144)   { long e = u * 8; int l = (int)(e >> 13); long rem = e & 8191;
                    ((short8*)wofaw)[(l * 24576 + 16384 + rem) >> 3] = cvt8(aw_w + e); return; } u -= 6144;
  if (u < 3840000){ ((short8*)src_b)[u]  = cvt8(src + u * 8); return; } u -= 3840000;
  if (u < 72) {
    long e0 = u * 8;
#pragma unroll
    for (int j = 0; j < 8; j++) {
      long e = e0 + j;
      if (e < 384) { int l = (int)(e >> 6); obc[l * 96 + (e & 63)] = off_b[e]; }
      else { long e2 = e - 384; int l = (int)(e2 >> 5); obc[l * 96 + 64 + (e2 & 31)] = aw_b[e2]; }
    }
  }
}

// ---------------------------------------------------------------------------
// vproj6_k: value projection for ALL 6 layers, layer loop inside the block.
// Round-2-proven structure (As staged once via global_load_lds; Cs-transposed
// full-line store epilogue; traffic exact: FETCH 42MB, WRITE 360MB) with Cs
// shrunk 32KB -> 8KB, drained in 4 FULLY-UNROLLED chunks/layer. LDS = 40KB
// -> 4 blocks/CU (160KB exactly), doubling round-2's in-flight write
// capacity. Two spill rules learned on this kernel, both enforced here:
//  (1) no launch_bounds min-waves (r4/r5: caps VGPR at 64 -> acc spills);
//  (2) chunk loop MUST be unrolled (r6: runtime-indexed acc[i] -> entire
//      accumulator in scratch; VGPR=84 + 5.7GB WRITE was the signature).
// ---------------------------------------------------------------------------
__global__ __launch_bounds__(256) void vproj6_k(
    const u16* __restrict__ A,       // src_b, lda = 256
    const u16* __restrict__ W,       // wval_b, 65536 elems per layer
    const float* __restrict__ bias,  // val_b, 256 per layer
    u16* __restrict__ C)             // vsrc, 30720000 elems per layer
{
  __shared__ u16 As[64 * 256];
  __shared__ u16 Cs[16 * 256];
  const int wave = threadIdx.x >> 6, lane = threadIdx.x & 63;
  const int bm = blockIdx.x * 64;
  const int bn = wave * 64;
  const int lr = lane & 15, lq = lane >> 4;
  // stage A once: 64 rows x 256 k, 16B per lane per iter, linear LDS dest
#pragma unroll
  for (int it = 0; it < 8; it++) {
    int ub = wave * 512 + it * 64;
    int u = ub + lane;
    int row = u & 63, kgrp = u >> 6;
    const u16* ga = A + (long)(bm + row) * 256 + kgrp * 8;
    __builtin_amdgcn_global_load_lds(
        (const __attribute__((address_space(1))) void*)ga,
        (__attribute__((address_space(3))) void*)(As + ub * 8), 16, 0, 0);
  }
  __syncthreads();
#pragma unroll 1
  for (int l = 0; l < 6; l++) {
    const u16* Wz = W + (long)l * 65536;
    f32x4 acc[4][4] = {};
#pragma unroll
    for (int s = 0; s < 8; s++) {
      short8 af[4], bf[4];
#pragma unroll
      for (int i = 0; i < 4; i++)
        af[i] = *(const short8*)(As + ((s * 4 + lq) * 64 + i * 16 + lr) * 8);
#pragma unroll
      for (int j = 0; j < 4; j++)
        bf[j] = *(const short8*)(Wz + (long)(bn + j * 16 + lr) * 256 + s * 32 + lq * 8);
#pragma unroll
      for (int i = 0; i < 4; i++)
#pragma unroll
        for (int j = 0; j < 4; j++)
          acc[i][j] = __builtin_amdgcn_mfma_f32_16x16x32_bf16(af[i], bf[j], acc[i][j], 0, 0, 0);
    }
    const float* bz = bias + l * 256;
    u16* Cl = C + (long)l * 30720000 + (long)bm * 256;
    // drain the 64x256 tile through an 8KB Cs in 4 chunks of 16 rows.
    // FULLY UNROLLED so every acc[i][j][r] index is compile-time constant.
#pragma unroll
    for (int i = 0; i < 4; i++) {
      __syncthreads();   // previous chunk's read-back complete
      // scatter: 32B-slot XOR swizzle; lq = rowl>>2 -> 4 disjoint 8-bank sets
#pragma unroll
      for (int j = 0; j < 4; j++) {
        int colt = bn + j * 16 + lr;
        float bv = bz[colt];
#pragma unroll
        for (int r = 0; r < 4; r++) {
          int rowl = lq * 4 + r;
          int byte = (rowl << 9) + (colt << 1);
          byte ^= ((rowl >> 2) & 3) << 5;
          *(u16*)((char*)Cs + byte) = f2b(acc[i][j][r] + bv);
        }
      }
      __syncthreads();
      // linear read-back + contiguous stores: 1KB per wave-op, full lines
#pragma unroll
      for (int t = 0; t < 2; t++) {
        int idx = t * 256 + threadIdx.x;
        int byte = idx << 4;
        byte ^= ((byte >> 11) & 3) << 5;  // rowl bits 2-3 = byte bits 11-12
        short8 v = *(const short8*)((const char*)Cs + byte);
        ((short8*)(Cl + (long)i * 4096))[idx] = v;
      }
    }
  }
}

// ---------------------------------------------------------------------------
// gemm_w_k<MT>: MT(M) x 256(N) block; 4 waves side-by-side (wave = 64 cols).
// A chunk (MT x 256) staged in LDS via global_load_lds(16B); W streamed (L2).
// z-batched via wZ/bZ/cZ strides. Optional RELU / bf16-out / fused V^T /
// fused residual+LayerNorm epilogue. Grid must exactly cover M (grid.x*MT)
// and N (grid.y*256); K % 256 == 0.
// ---------------------------------------------------------------------------
template<int MT, bool RELU, bool OUTBF, bool VT, bool LN>
__global__ __launch_bounds__(256) void gemm_w_k(
    const u16* __restrict__ A, int lda,
    const u16* __restrict__ W, long wZ,
    const float* __restrict__ bias, int bZ,
    void* __restrict__ Cv, int ldo, long cZ,
    int K,
    u16* __restrict__ vt,
    const float* __restrict__ res,
    const float* __restrict__ lnw, const float* __restrict__ lnb,
    const float* __restrict__ qpos,
    float* __restrict__ out_f, u16* __restrict__ out_b16,
    u16* __restrict__ qk_b16, float* __restrict__ hsp)
{
  __shared__ u16 As[32 * MT * 8];
  __shared__ float r1s[4][64], r2s[4][64], mArr[64], iArr[64];
  const int wave = threadIdx.x >> 6, lane = threadIdx.x & 63;
  const int bm = blockIdx.x * MT;
  const int bn = blockIdx.y * 256 + wave * 64;
  const int lr = lane & 15, lq = lane >> 4;
  constexpr int SH = (MT == 64) ? 6 : 5;
  const u16* Wz = W + (long)blockIdx.z * wZ;
  const float* bz = bias + (long)blockIdx.z * bZ;
  f32x4 acc[MT / 16][4] = {};
  const int nchunks = K >> 8;
  for (int ch = 0; ch < nchunks; ch++) {
#pragma unroll
    for (int it = 0; it < MT / 8; it++) {
      int ub = wave * (MT * 8) + it * 64;
      int u = ub + lane;
      int row = u & (MT - 1), kgrp = u >> SH;
      const u16* ga = A + (long)(bm + row) * lda + ch * 256 + kgrp * 8;
      __builtin_amdgcn_global_load_lds(
          (const __attribute__((address_space(1))) void*)ga,
          (__attribute__((address_space(3))) void*)(As + ub * 8), 16, 0, 0);
    }
    __syncthreads();
#pragma unroll
    for (int s = 0; s < 8; s++) {
      short8 af[MT / 16], bf[4];
#pragma unroll
      for (int i = 0; i < MT / 16; i++)
        af[i] = *(const short8*)(As + ((s * 4 + lq) * MT + i * 16 + lr) * 8);
#pragma unroll
      for (int j = 0; j < 4; j++) {
        int cc = bn + j * 16 + lr;
        bf[j] = *(const short8*)(Wz + (long)cc * K + ch * 256 + s * 32 + lq * 8);
      }
#pragma unroll
      for (int i = 0; i < MT / 16; i++)
#pragma unroll
        for (int j = 0; j < 4; j++)
          acc[i][j] = __builtin_amdgcn_mfma_f32_16x16x32_bf16(af[i], bf[j], acc[i][j], 0, 0, 0);
    }
    __syncthreads();
  }

  float bv[4];
#pragma unroll
  for (int j = 0; j < 4; j++) bv[j] = bz[bn + j * 16 + lr];

  if (!LN) {
    char* Cz = (char*)Cv;
#pragma unroll
    for (int j = 0; j < 4; j++) {
      int cc = bn + j * 16 + lr;
#pragma unroll
      for (int i = 0; i < MT / 16; i++) {
#pragma unroll
        for (int r = 0; r < 4; r++) {
          int rr = bm + i * 16 + lq * 4 + r;
          float v = acc[i][j][r] + bv[j];
          if (RELU) v = fmaxf(v, 0.f);
          long idx = (long)blockIdx.z * cZ + (long)rr * ldo + cc;
          if (OUTBF) ((u16*)Cz)[idx] = f2b(v);
          else       ((float*)Cz)[idx] = v;
          if (VT) {
            int b_ = rr >> 10, q_ = rr & 1023, h_ = cc >> 5, dh_ = cc & 31;
            vt[(long)((((b_ << 3) + h_) << 5) + dh_) * 1024 + q_] = f2b(v);
          }
        }
      }
    }
  } else {
    float s1[MT / 16][4] = {}, s2[MT / 16][4] = {};
#pragma unroll
    for (int i = 0; i < MT / 16; i++) {
#pragma unroll
      for (int r = 0; r < 4; r++) {
        int rowg = bm + i * 16 + lq * 4 + r;
#pragma unroll
        for (int j = 0; j < 4; j++) {
          int cc = bn + j * 16 + lr;
          float x = acc[i][j][r] + bv[j] + res[(long)rowg * 256 + cc];
          s1[i][r] += x; s2[i][r] += x * x;
        }
      }
    }
#pragma unroll
    for (int i = 0; i < MT / 16; i++)
#pragma unroll
      for (int r = 0; r < 4; r++) {
#pragma unroll
        for (int m = 1; m <= 8; m <<= 1) {
          s1[i][r] += __shfl_xor(s1[i][r], m);
          s2[i][r] += __shfl_xor(s2[i][r], m);
        }
      }
    if (lr == 0) {
#pragma unroll
      for (int i = 0; i < MT / 16; i++)
#pragma unroll
        for (int r = 0; r < 4; r++) {
          int rl = i * 16 + lq * 4 + r;
          r1s[wave][rl] = s1[i][r];
          r2s[wave][rl] = s2[i][r];
        }
    }
    __syncthreads();
    if (threadIdx.x < MT) {
      int t = threadIdx.x;
      float a = r1s[0][t] + r1s[1][t] + r1s[2][t] + r1s[3][t];
      float b = r2s[0][t] + r2s[1][t] + r2s[2][t] + r2s[3][t];
      float m = a * (1.f / 256.f);
      float var = b * (1.f / 256.f) - m * m;
      mArr[t] = m;
      iArr[t] = rsqrtf(var + 1e-5f);
    }
    __syncthreads();
#pragma unroll
    for (int i = 0; i < MT / 16; i++) {
#pragma unroll
      for (int r = 0; r < 4; r++) {
        int rl = i * 16 + lq * 4 + r;
        int rowg = bm + rl;
        float m = mArr[rl], inv = iArr[rl];
#pragma unroll
        for (int j = 0; j < 4; j++) {
          int cc = bn + j * 16 + lr;
          long idx = (long)rowg * 256 + cc;
          float x = acc[i][j][r] + bv[j] + res[idx];
          float y = (x - m) * inv * lnw[cc] + lnb[cc];
          out_f[idx] = y;
          if (out_b16) out_b16[idx] = f2b(y);
          if (qk_b16)  qk_b16[idx]  = f2b(y + qpos[idx]);
          if (hsp)     hsp[idx]     = y;
        }
      }
    }
  }
}

// ---------------------------------------------------------------------------
// qkv_k: merged Q/K/V projection. grid (64, 3): y=0 -> Q cols of qkbuf,
// y=1 -> K cols, y=2 -> V (writes vt only). MT=64 core identical to gemm_w_k.
// ---------------------------------------------------------------------------
__global__ __launch_bounds__(256) void qkv_k(
    const u16* __restrict__ qk_b, const u16* __restrict__ out_b,
    const u16* __restrict__ wsa, const float* __restrict__ bsa,
    u16* __restrict__ qkbuf, u16* __restrict__ vt)
{
  __shared__ u16 As[32 * 64 * 8];
  const int sel = blockIdx.y;
  const u16* A = (sel == 2) ? out_b : qk_b;
  const u16* W = wsa + (long)sel * 256 * 256;
  const int wave = threadIdx.x >> 6, lane = threadIdx.x & 63;
  const int bm = blockIdx.x * 64;
  const int bn = wave * 64;
  const int lr = lane & 15, lq = lane >> 4;
  f32x4 acc[4][4] = {};
#pragma unroll
  for (int it = 0; it < 8; it++) {
    int ub = wave * 512 + it * 64;
    int u = ub + lane;
    int row = u & 63, kgrp = u >> 6;
    const u16* ga = A + (long)(bm + row) * 256 + kgrp * 8;
    __builtin_amdgcn_global_load_lds(
        (const __attribute__((address_space(1))) void*)ga,
        (__attribute__((address_space(3))) void*)(As + ub * 8), 16, 0, 0);
  }
  __syncthreads();
#pragma unroll
  for (int s = 0; s < 8; s++) {
    short8 af[4], bf[4];
#pragma unroll
    for (int i = 0; i < 4; i++)
      af[i] = *(const short8*)(As + ((s * 4 + lq) * 64 + i * 16 + lr) * 8);
#pragma unroll
    for (int j = 0; j < 4; j++) {
      int cc = bn + j * 16 + lr;
      bf[j] = *(const short8*)(W + (long)cc * 256 + s * 32 + lq * 8);
    }
#pragma unroll
    for (int i = 0; i < 4; i++)
#pragma unroll
      for (int j = 0; j < 4; j++)
        acc[i][j] = __builtin_amdgcn_mfma_f32_16x16x32_bf16(af[i], bf[j], acc[i][j], 0, 0, 0);
  }
  float bv[4];
#pragma unroll
  for (int j = 0; j < 4; j++) bv[j] = bsa[sel * 256 + bn + j * 16 + lr];
#pragma unroll
  for (int j = 0; j < 4; j++) {
    int cc = bn + j * 16 + lr;
#pragma unroll
    for (int i = 0; i < 4; i++) {
#pragma unroll
      for (int r = 0; r < 4; r++) {
        int rr = bm + i * 16 + lq * 4 + r;
        float v = acc[i][j][r] + bv[j];
        if (sel < 2) {
          qkbuf[(long)rr * 512 + sel * 256 + cc] = f2b(v);
        } else {
          int b_ = rr >> 10, q_ = rr & 1023, h_ = cc >> 5, dh_ = cc & 31;
          vt[(long)((((b_ << 3) + h_) << 5) + dh_) * 1024 + q_] = f2b(v);
        }
      }
    }
  }
}

// ---------------------------------------------------------------------------
// Flash self-attention (round-6 proven): block per (b,h,q-tile 128).
// ---------------------------------------------------------------------------
__global__ __launch_bounds__(256) void flash_k(
    const u16* __restrict__ qkbuf, const u16* __restrict__ vt,
    u16* __restrict__ obuf)
{
  const float SC = 0.17677669529663687f;
  __shared__ u16 Plds[4][32][136];
  const int bh = blockIdx.x >> 3;
  const int b = bh >> 3, h = bh & 7;
  const int qt = blockIdx.x & 7;
  const int wave = threadIdx.x >> 6, lane = threadIdx.x & 63;
  const int lr = lane & 15, lq = lane >> 4;
  const int qbase = qt * 128 + wave * 32;

  short8 qf[2];
#pragma unroll
  for (int i = 0; i < 2; i++)
    qf[i] = *(const short8*)(qkbuf + (long)(b * 1024 + qbase + i * 16 + lr) * 512 + h * 32 + lq * 8);

  const u16* Kb = qkbuf + (long)b * 1024 * 512 + 256 + h * 32;
  const u16* Vb = vt + (long)bh * 32 * 1024;

  f32x4 acc_o[2][2] = {};
  float m_run[2][4], l_run[2][4];
#pragma unroll
  for (int i = 0; i < 2; i++)
#pragma unroll
    for (int r = 0; r < 4; r++){ m_run[i][r] = -3e38f; l_run[i][r] = 0.f; }

  for (int kt = 0; kt < 8; kt++) {
    f32x4 s[2][8] = {};
#pragma unroll
    for (int j = 0; j < 8; j++) {
      short8 kf = *(const short8*)(Kb + (long)(kt * 128 + j * 16 + lr) * 512 + lq * 8);
#pragma unroll
      for (int i = 0; i < 2; i++)
        s[i][j] = __builtin_amdgcn_mfma_f32_16x16x32_bf16(qf[i], kf, s[i][j], 0, 0, 0);
    }
#pragma unroll
    for (int i = 0; i < 2; i++) {
#pragma unroll
      for (int r = 0; r < 4; r++) {
        float mx = s[i][0][r];
#pragma unroll
        for (int j = 1; j < 8; j++) mx = fmaxf(mx, s[i][j][r]);
#pragma unroll
        for (int m = 1; m <= 8; m <<= 1) mx = fmaxf(mx, __shfl_xor(mx, m));
        float m_new = fmaxf(m_run[i][r], mx);
        float alpha = __expf((m_run[i][r] - m_new) * SC);
        float sum = 0.f;
        int row = i * 16 + lq * 4 + r;
#pragma unroll
        for (int j = 0; j < 8; j++) {
          float p = __expf((s[i][j][r] - m_new) * SC);
          sum += p;
          Plds[wave][row][j * 16 + lr] = f2b(p);
        }
#pragma unroll
        for (int m = 1; m <= 8; m <<= 1) sum += __shfl_xor(sum, m);
        l_run[i][r] = l_run[i][r] * alpha + sum;
        m_run[i][r] = m_new;
#pragma unroll
        for (int d = 0; d < 2; d++) acc_o[i][d][r] *= alpha;
      }
    }
#pragma unroll
    for (int kc = 0; kc < 4; kc++) {
      short8 pf[2];
#pragma unroll
      for (int i = 0; i < 2; i++)
        pf[i] = *(const short8*)&Plds[wave][i * 16 + lr][kc * 32 + lq * 8];
#pragma unroll
      for (int d = 0; d < 2; d++) {
        short8 vf = *(const short8*)(Vb + (long)(d * 16 + lr) * 1024 + kt * 128 + kc * 32 + lq * 8);
#pragma unroll
        for (int i = 0; i < 2; i++)
          acc_o[i][d] = __builtin_amdgcn_mfma_f32_16x16x32_bf16(pf[i], vf, acc_o[i][d], 0, 0, 0);
      }
    }
  }
#pragma unroll
  for (int i = 0; i < 2; i++) {
#pragma unroll
    for (int r = 0; r < 4; r++) {
      float inv = 1.f / l_run[i][r];
      int q = qbase + i * 16 + lq * 4 + r;
#pragma unroll
      for (int d = 0; d < 2; d++)
        obuf[(long)(b * 1024 + q) * 256 + h * 32 + d * 16 + lr] = f2b(acc_o[i][d][r] * inv);
    }
  }
}

// ---------------------------------------------------------------------------
// gemm64_k (bf16-only): 64x64 block, direct loads. Used for offaw (N=96).
// ---------------------------------------------------------------------------
__global__ __launch_bounds__(256) void gemm64_k(
    const u16* __restrict__ A, int lda,
    const u16* __restrict__ W, int ldw,
    const float* __restrict__ bias,
    float* __restrict__ C, int ldo,
    int M, int N, int K)
{
  const int wave = threadIdx.x >> 6, lane = threadIdx.x & 63;
  const int wm = wave >> 1, wn = wave & 1;
  const int bm = blockIdx.x * 64 + wm * 32;
  const int bn = blockIdx.y * 64 + wn * 32;
  const int lr = lane & 15, lq = lane >> 4;
  const int koff = lq * 8;
  f32x4 acc[2][2] = {};
  const short8 Z8 = {0,0,0,0,0,0,0,0};
  for (int k0 = 0; k0 < K; k0 += 32) {
    short8 af[2], bf[2];
#pragma unroll
    for (int i = 0; i < 2; i++) {
      int r = bm + i * 16 + lr;
      af[i] = (r < M) ? *(const short8*)(A + (long)r * lda + k0 + koff) : Z8;
    }
#pragma unroll
    for (int j = 0; j < 2; j++) {
      int c = bn + j * 16 + lr;
      bf[j] = (c < N) ? *(const short8*)(W + (long)c * ldw + k0 + koff) : Z8;
    }
#pragma unroll
    for (int i = 0; i < 2; i++)
#pragma unroll
      for (int j = 0; j < 2; j++)
        acc[i][j] = __builtin_amdgcn_mfma_f32_16x16x32_bf16(af[i], bf[j], acc[i][j], 0, 0, 0);
  }
#pragma unroll
  for (int j = 0; j < 2; j++) {
    int cc = bn + j * 16 + lr;
    if (cc >= N) continue;
    float bv = bias[cc];
#pragma unroll
    for (int i = 0; i < 2; i++) {
#pragma unroll
      for (int r = 0; r < 4; r++) {
        int rr = bm + i * 16 + lq * 4 + r;
        if (rr >= M) continue;
        C[(long)rr * ldo + cc] = acc[i][j][r] + bv;
      }
    }
  }
}

__global__ __launch_bounds__(256) void init_prep_k(const float* __restrict__ q, const float* __restrict__ qpos,
                                                   float* __restrict__ out_f, u16* __restrict__ out_b,
                                                   u16* __restrict__ qk_b){
  long i = (long)blockIdx.x * 256 + threadIdx.x;
  float o = q[i];
  out_f[i] = o;
  out_b[i] = f2b(o);
  qk_b[i]  = f2b(o + qpos[i]);
}

__global__ __launch_bounds__(256) void msda_k(
    const float* __restrict__ refp,
    const float* __restrict__ off, int ldoff,
    const float* __restrict__ aw, int ldaw,
    const u16* __restrict__ v,
    u16* __restrict__ o,
    long vstride)
{
  int tid = blockIdx.x * 256 + threadIdx.x;
  int dh = tid & 31;
  int h  = (tid >> 5) & 7;
  int bq = tid >> 8;
  int b  = bq >> 10;
  float rx = refp[bq * 2 + 0];
  float ry = refp[bq * 2 + 1];
  const float* offp = off + (long)bq * ldoff + h * 8;
  const float* awp  = aw  + (long)bq * ldaw + h * 4;
  float a0 = awp[0], a1 = awp[1], a2 = awp[2], a3 = awp[3];
  float am = fmaxf(fmaxf(a0, a1), fmaxf(a2, a3));
  float e[4];
  e[0] = __expf(a0 - am); e[1] = __expf(a1 - am); e[2] = __expf(a2 - am); e[3] = __expf(a3 - am);
  float einv = 1.f / (e[0] + e[1] + e[2] + e[3]);
  const u16* vb = v + b * vstride + h * 32 + dh;
  float accv = 0.f;
#pragma unroll
  for (int pp = 0; pp < 4; pp++){
    float x = rx * 150.f + offp[pp * 2 + 0] - 0.5f;
    float y = ry * 200.f + offp[pp * 2 + 1] - 0.5f;
    float x0 = floorf(x), y0 = floorf(y);
    float s = 0.f;
#pragma unroll
    for (int c = 0; c < 4; c++){
      int dx = c & 1, dy = c >> 1;
      float xi = x0 + dx, yi = y0 + dy;
      float wt = (1.f - fabsf(x - xi)) * (1.f - fabsf(y - yi));
      if (xi >= 0.f && xi < 150.f && yi >= 0.f && yi < 200.f && wt > 0.f) {
        int xc = (int)xi, yc = (int)yi;
        s += wt * b2f(vb[((long)yc * 150 + xc) * 256]);
      }
    }
    accv += e[pp] * einv * s;
  }
  o[(long)bq * 256 + h * 32 + dh] = f2b(accv);
}

__global__ __launch_bounds__(256) void refs_k(const float* __restrict__ r, float* __restrict__ dst){
  int i = blockIdx.x * 256 + threadIdx.x;
  dst[i] = r[i & 8191];
}

// ---------------------------------------------------------------------------
extern "C" void kernel_launch(void* const* d_in, const int* in_sizes, int n_in,
                              void* d_out, int out_size, void* d_ws, size_t ws_size,
                              hipStream_t stream)
{
  (void)in_sizes; (void)n_in; (void)out_size;
  const float* query = (const float*)d_in[0];
  const float* qpos  = (const float*)d_in[1];
  const float* refp  = (const float*)d_in[2];
  const float* src   = (const float*)d_in[3];
  const float* sa_in_w  = (const float*)d_in[6];
  const float* sa_in_b  = (const float*)d_in[7];
  const float* sa_out_w = (const float*)d_in[8];
  const float* sa_out_b = (const float*)d_in[9];
  const float* off_w = (const float*)d_in[10];
  const float* off_b = (const float*)d_in[11];
  const float* aw_w  = (const float*)d_in[12];
  const float* aw_b  = (const float*)d_in[13];
  const float* val_w = (const float*)d_in[14];
  const float* val_b = (const float*)d_in[15];
  const float* cout_w = (const float*)d_in[16];
  const float* cout_b = (const float*)d_in[17];
  const float* n1w = (const float*)d_in[18]; const float* n1b = (const float*)d_in[19];
  const float* n2w = (const float*)d_in[20]; const float* n2b = (const float*)d_in[21];
  const float* n3w = (const float*)d_in[22]; const float* n3b = (const float*)d_in[23];
  const float* ff1w = (const float*)d_in[24]; const float* ff1b = (const float*)d_in[25];
  const float* ff2w = (const float*)d_in[26]; const float* ff2b = (const float*)d_in[27];

  float* hs = (float*)d_out;
  float* refs_out = hs + (long)6 * 4096 * 256;

  char* p = (char*)d_ws;
  auto alloc = [&](size_t bytes){ char* r = p; p += (bytes + 255) & ~(size_t)255; return r; };
  float* out_f = (float*)alloc(4194304);
  u16*   qk_b  = (u16*)  alloc(2097152);
  u16*   out_b = (u16*)  alloc(2097152);
  u16* wsa_b  = (u16*)alloc(2359296);
  u16* wsao_b = (u16*)alloc(786432);
  u16* wofaw  = (u16*)alloc(294912);
  u16* wval_b = (u16*)alloc(786432);
  u16* wcao_b = (u16*)alloc(786432);
  u16* wff1_b = (u16*)alloc(3145728);
  u16* wff2_b = (u16*)alloc(3145728);
  float* obc  = (float*)alloc(2304);
  u16* src_b  = (u16*)alloc(61440000);
  u16* qkbuf  = (u16*)alloc(4194304);
  u16* vt     = (u16*)alloc(2097152);
  u16* obuf   = (u16*)alloc(2097152);
  float* oawo = (float*)alloc(1572864);
  u16* mo     = (u16*)alloc(2097152);
  u16* ffh    = (u16*)alloc(8388608);
  size_t used = (size_t)(p - (char*)d_ws);
  const bool big = (ws_size >= used + 368640000ull);   // room for 6-layer vsrc
  u16* vsrc = (u16*)alloc(big ? 368640000ull : 61440000ull);

  init_prep_k<<<4096, 256, 0, stream>>>(query, qpos, out_f, out_b, qk_b);
  cvtall_k<<<17761, 256, 0, stream>>>(sa_in_w, sa_out_w, val_w, cout_w, ff1w, ff2w,
                                      off_w, aw_w, off_b, aw_b, src,
                                      wsa_b, wsao_b, wval_b, wcao_b, wff1_b, wff2_b,
                                      wofaw, obc, src_b);
  if (big) {
    // all 6 layers' value projections in one launch, layer loop INSIDE the
    // block: A-tile staged once, 8KB-chunked (unrolled) Cs store epilogue.
    vproj6_k<<<1875, 256, 0, stream>>>(src_b, wval_b, val_b, vsrc);
  }

  for (int l = 0; l < 6; l++){
    const u16* wsa = wsa_b + (long)l * 768 * 256;
    // ---- self attention (flash) ----
    qkv_k<<<dim3(64,3,1),256,0,stream>>>(qk_b, out_b, wsa, sa_in_b + l * 768, qkbuf, vt);
    flash_k<<<256,256,0,stream>>>(qkbuf, vt, obuf);
    gemm_w_k<32,false,false,false,true><<<dim3(128,1,1),256,0,stream>>>(   // out-proj + norm2
        obuf, 256, wsao_b + (long)l*65536, 0, sa_out_b + l*256, 0, nullptr, 0, 0, 256,
        nullptr, out_f, n2w + l*256, n2b + l*256, qpos, out_f, nullptr, qk_b, nullptr);
    // ---- deformable cross attention ----
    gemm64_k<<<dim3(64,2,1),256,0,stream>>>(qk_b, 256, wofaw + (long)l*24576, 256,
        obc + l*96, oawo, 96, 4096, 96, 256);
    if (!big) {
      gemm_w_k<64,false,true,false,false><<<dim3(1875,1,1),256,0,stream>>>(
          src_b, 256, wval_b + (long)l*65536, 0, val_b + l*256, 0, vsrc, 256, 0, 256,
          nullptr, nullptr,nullptr,nullptr,nullptr,nullptr,nullptr,nullptr,nullptr);
    }
    const u16* vsl = big ? (vsrc + (long)l*30720000) : vsrc;
    msda_k<<<4096,256,0,stream>>>(refp, oawo, 96, oawo + 64, 96, vsl, mo, 7680000);
    gemm_w_k<32,false,false,false,true><<<dim3(128,1,1),256,0,stream>>>(   // ca-out + norm1
        mo, 256, wcao_b + (long)l*65536, 0, cout_b + l*256, 0, nullptr, 0, 0, 256,
        nullptr, out_f, n1w + l*256, n1b + l*256, nullptr, out_f, out_b, nullptr, nullptr);
    // ---- ffn ----
    gemm_w_k<64,true,true,false,false><<<dim3(64,4,1),256,0,stream>>>(     // ff1 + relu
        out_b, 256, wff1_b + (long)l*262144, 0, ff1b + l*1024, 0, ffh, 1024, 0, 256,
        nullptr, nullptr,nullptr,nullptr,nullptr,nullptr,nullptr,nullptr,nullptr);
    gemm_w_k<32,false,false,false,true><<<dim3(128,1,1),256,0,stream>>>(   // ff2 + norm3
        ffh, 1024, wff2_b + (long)l*262144, 0, ff2b + l*256, 0, nullptr, 0, 0, 1024,
        nullptr, out_f, n3w + l*256, n3b + l*256, qpos, out_f, out_b, qk_b,
        hs + (long)l*1048576);
  }
  refs_k<<<192,256,0,stream>>>(refp, refs_out);
}

// Round 8
// 1567.369 us; speedup vs baseline: 1.5745x; 1.0710x over previous
//
#include <hip/hip_runtime.h>

typedef __attribute__((ext_vector_type(8))) short short8;
typedef __attribute__((ext_vector_type(4))) float f32x4;
typedef unsigned short u16;

#define DEVI static __device__ __forceinline__

// BS=4 NQ=1024 D=256 NH=8 NP=4 L=6 DFF=1024 H=200 W=150 NV=30000 DH=32
// d_in/d_out are FP32. Internals: bf16 MFMA, fp32 accum, fp32 residual+LN.
DEVI float b2f(u16 u){ unsigned int x = ((unsigned int)u) << 16; float f; __builtin_memcpy(&f, &x, 4); return f; }
DEVI u16 f2b(float f){ unsigned int u; __builtin_memcpy(&u, &f, 4); u += 0x7fffu + ((u >> 16) & 1u); return (u16)(u >> 16); }
DEVI short8 cvt8(const float* __restrict__ p){
  f32x4 a = *(const f32x4*)p;
  f32x4 b = *(const f32x4*)(p + 4);
  short8 r;
  r[0]=(short)f2b(a[0]); r[1]=(short)f2b(a[1]); r[2]=(short)f2b(a[2]); r[3]=(short)f2b(a[3]);
  r[4]=(short)f2b(b[0]); r[5]=(short)f2b(b[1]); r[6]=(short)f2b(b[2]); r[7]=(short)f2b(b[3]);
  return r;
}

// ---------------------------------------------------------------------------
// One-shot convert/pack of ALL fp32 params -> bf16 (plus obc fp32 pack).
// Unit = 8 elements. Segment sizes in units; see launcher for grid math.
// ---------------------------------------------------------------------------
__global__ __launch_bounds__(256) void cvtall_k(
    const float* __restrict__ sa_in_w, const float* __restrict__ sa_out_w,
    const float* __restrict__ val_w,   const float* __restrict__ cout_w,
    const float* __restrict__ ff1w,    const float* __restrict__ ff2w,
    const float* __restrict__ off_w,   const float* __restrict__ aw_w,
    const float* __restrict__ off_b,   const float* __restrict__ aw_b,
    const float* __restrict__ src,
    u16* __restrict__ wsa_b, u16* __restrict__ wsao_b, u16* __restrict__ wval_b,
    u16* __restrict__ wcao_b, u16* __restrict__ wff1_b, u16* __restrict__ wff2_b,
    u16* __restrict__ wofaw, float* __restrict__ obc, u16* __restrict__ src_b)
{
  long u = (long)blockIdx.x * 256 + threadIdx.x;
  if (u < 147456) { ((short8*)wsa_b)[u]  = cvt8(sa_in_w  + u * 8); return; } u -= 147456;
  if (u < 49152)  { ((short8*)wsao_b)[u] = cvt8(sa_out_w + u * 8); return; } u -= 49152;
  if (u < 49152)  { ((short8*)wval_b)[u] = cvt8(val_w    + u * 8); return; } u -= 49152;
  if (u < 49152)  { ((short8*)wcao_b)[u] = cvt8(cout_w   + u * 8); return; } u -= 49152;
  if (u < 196608) { ((short8*)wff1_b)[u] = cvt8(ff1w     + u * 8); return; } u -= 196608;
  if (u < 196608) { ((short8*)wff2_b)[u] = cvt8(ff2w     + u * 8); return; } u -= 196608;
  if (u < 12288)  { long e = u * 8; int l = (int)(e >> 14); long rem = e & 16383;
                    ((short8*)wofaw)[(l * 24576 + rem) >> 3] = cvt8(off_w + e); return; } u -= 12288;
  if (u < 6144)   { long e = u * 8; int l = (int)(e >> 13); long rem = e & 8191;
                    ((short8*)wofaw)[(l * 24576 + 16384 + rem) >> 3] = cvt8(aw_w + e); return; } u -= 6144;
  if (u < 3840000){ ((short8*)src_b)[u]  = cvt8(src + u * 8); return; } u -= 3840000;
  if (u < 72) {
    long e0 = u * 8;
#pragma unroll
    for (int j = 0; j < 8; j++) {
      long e = e0 + j;
      if (e < 384) { int l = (int)(e >> 6); obc[l * 96 + (e & 63)] = off_b[e]; }
      else { long e2 = e - 384; int l = (int)(e2 >> 5); obc[l * 96 + 64 + (e2 & 31)] = aw_b[e2]; }
    }
  }
}

// ---------------------------------------------------------------------------
// vproj6_k (round-7 proven, 257us, traffic-exact): value projection for ALL
// 6 layers, layer loop inside the block. As staged once; 8KB chunked Cs
// transposed epilogue (full-line stores). Spill rules: no min-waves bound;
// all accumulator indices compile-time constant.
// ---------------------------------------------------------------------------
__global__ __launch_bounds__(256) void vproj6_k(
    const u16* __restrict__ A,       // src_b, lda = 256
    const u16* __restrict__ W,       // wval_b, 65536 elems per layer
    const float* __restrict__ bias,  // val_b, 256 per layer
    u16* __restrict__ C)             // vsrc, 30720000 elems per layer
{
  __shared__ u16 As[64 * 256];
  __shared__ u16 Cs[16 * 256];
  const int wave = threadIdx.x >> 6, lane = threadIdx.x & 63;
  const int bm = blockIdx.x * 64;
  const int bn = wave * 64;
  const int lr = lane & 15, lq = lane >> 4;
#pragma unroll
  for (int it = 0; it < 8; it++) {
    int ub = wave * 512 + it * 64;
    int u = ub + lane;
    int row = u & 63, kgrp = u >> 6;
    const u16* ga = A + (long)(bm + row) * 256 + kgrp * 8;
    __builtin_amdgcn_global_load_lds(
        (const __attribute__((address_space(1))) void*)ga,
        (__attribute__((address_space(3))) void*)(As + ub * 8), 16, 0, 0);
  }
  __syncthreads();
#pragma unroll 1
  for (int l = 0; l < 6; l++) {
    const u16* Wz = W + (long)l * 65536;
    f32x4 acc[4][4] = {};
#pragma unroll
    for (int s = 0; s < 8; s++) {
      short8 af[4], bf[4];
#pragma unroll
      for (int i = 0; i < 4; i++)
        af[i] = *(const short8*)(As + ((s * 4 + lq) * 64 + i * 16 + lr) * 8);
#pragma unroll
      for (int j = 0; j < 4; j++)
        bf[j] = *(const short8*)(Wz + (long)(bn + j * 16 + lr) * 256 + s * 32 + lq * 8);
#pragma unroll
      for (int i = 0; i < 4; i++)
#pragma unroll
        for (int j = 0; j < 4; j++)
          acc[i][j] = __builtin_amdgcn_mfma_f32_16x16x32_bf16(af[i], bf[j], acc[i][j], 0, 0, 0);
    }
    const float* bz = bias + l * 256;
    u16* Cl = C + (long)l * 30720000 + (long)bm * 256;
#pragma unroll
    for (int i = 0; i < 4; i++) {
      __syncthreads();
#pragma unroll
      for (int j = 0; j < 4; j++) {
        int colt = bn + j * 16 + lr;
        float bv = bz[colt];
#pragma unroll
        for (int r = 0; r < 4; r++) {
          int rowl = lq * 4 + r;
          int byte = (rowl << 9) + (colt << 1);
          byte ^= ((rowl >> 2) & 3) << 5;
          *(u16*)((char*)Cs + byte) = f2b(acc[i][j][r] + bv);
        }
      }
      __syncthreads();
#pragma unroll
      for (int t = 0; t < 2; t++) {
        int idx = t * 256 + threadIdx.x;
        int byte = idx << 4;
        byte ^= ((byte >> 11) & 3) << 5;
        short8 v = *(const short8*)((const char*)Cs + byte);
        ((short8*)(Cl + (long)i * 4096))[idx] = v;
      }
    }
  }
}

// ---------------------------------------------------------------------------
// gemm_w_k<MT>: MT(M) x 256(N) block; 4 waves side-by-side (wave = 64 cols).
// DIRECT A loads (no LDS staging): at K=256 the staged A-tile is used once
// per wave, and the staging's vmcnt(0) barrier drain serializes the whole
// small kernel (round-0 diagnosis, now applied chain-wide). A buffers are
// 2-8MB L2/L3-resident; 4x wave redundancy is cheap L2 traffic.
// z-batched via wZ/bZ/cZ strides. Optional RELU / bf16-out / fused V^T /
// fused residual+LayerNorm epilogue. Grid covers M (grid.x*MT), N (grid.y*256);
// K % 256 == 0.
// ---------------------------------------------------------------------------
template<int MT, bool RELU, bool OUTBF, bool VT, bool LN>
__global__ __launch_bounds__(256) void gemm_w_k(
    const u16* __restrict__ A, int lda,
    const u16* __restrict__ W, long wZ,
    const float* __restrict__ bias, int bZ,
    void* __restrict__ Cv, int ldo, long cZ,
    int K,
    u16* __restrict__ vt,
    const float* __restrict__ res,
    const float* __restrict__ lnw, const float* __restrict__ lnb,
    const float* __restrict__ qpos,
    float* __restrict__ out_f, u16* __restrict__ out_b16,
    u16* __restrict__ qk_b16, float* __restrict__ hsp)
{
  __shared__ float r1s[4][64], r2s[4][64], mArr[64], iArr[64];
  const int wave = threadIdx.x >> 6, lane = threadIdx.x & 63;
  const int bm = blockIdx.x * MT;
  const int bn = blockIdx.y * 256 + wave * 64;
  const int lr = lane & 15, lq = lane >> 4;
  const u16* Wz = W + (long)blockIdx.z * wZ;
  const float* bz = bias + (long)blockIdx.z * bZ;
  f32x4 acc[MT / 16][4] = {};
  const int nchunks = K >> 8;
  for (int ch = 0; ch < nchunks; ch++) {
#pragma unroll
    for (int s = 0; s < 8; s++) {
      short8 af[MT / 16], bf[4];
#pragma unroll
      for (int i = 0; i < MT / 16; i++)
        af[i] = *(const short8*)(A + (long)(bm + i * 16 + lr) * lda + ch * 256 + (s * 4 + lq) * 8);
#pragma unroll
      for (int j = 0; j < 4; j++) {
        int cc = bn + j * 16 + lr;
        bf[j] = *(const short8*)(Wz + (long)cc * K + ch * 256 + s * 32 + lq * 8);
      }
#pragma unroll
      for (int i = 0; i < MT / 16; i++)
#pragma unroll
        for (int j = 0; j < 4; j++)
          acc[i][j] = __builtin_amdgcn_mfma_f32_16x16x32_bf16(af[i], bf[j], acc[i][j], 0, 0, 0);
    }
  }

  float bv[4];
#pragma unroll
  for (int j = 0; j < 4; j++) bv[j] = bz[bn + j * 16 + lr];

  if (!LN) {
    char* Cz = (char*)Cv;
#pragma unroll
    for (int j = 0; j < 4; j++) {
      int cc = bn + j * 16 + lr;
#pragma unroll
      for (int i = 0; i < MT / 16; i++) {
#pragma unroll
        for (int r = 0; r < 4; r++) {
          int rr = bm + i * 16 + lq * 4 + r;
          float v = acc[i][j][r] + bv[j];
          if (RELU) v = fmaxf(v, 0.f);
          long idx = (long)blockIdx.z * cZ + (long)rr * ldo + cc;
          if (OUTBF) ((u16*)Cz)[idx] = f2b(v);
          else       ((float*)Cz)[idx] = v;
          if (VT) {
            int b_ = rr >> 10, q_ = rr & 1023, h_ = cc >> 5, dh_ = cc & 31;
            vt[(long)((((b_ << 3) + h_) << 5) + dh_) * 1024 + q_] = f2b(v);
          }
        }
      }
    }
  } else {
    float s1[MT / 16][4] = {}, s2[MT / 16][4] = {};
#pragma unroll
    for (int i = 0; i < MT / 16; i++) {
#pragma unroll
      for (int r = 0; r < 4; r++) {
        int rowg = bm + i * 16 + lq * 4 + r;
#pragma unroll
        for (int j = 0; j < 4; j++) {
          int cc = bn + j * 16 + lr;
          float x = acc[i][j][r] + bv[j] + res[(long)rowg * 256 + cc];
          s1[i][r] += x; s2[i][r] += x * x;
        }
      }
    }
#pragma unroll
    for (int i = 0; i < MT / 16; i++)
#pragma unroll
      for (int r = 0; r < 4; r++) {
#pragma unroll
        for (int m = 1; m <= 8; m <<= 1) {
          s1[i][r] += __shfl_xor(s1[i][r], m);
          s2[i][r] += __shfl_xor(s2[i][r], m);
        }
      }
    if (lr == 0) {
#pragma unroll
      for (int i = 0; i < MT / 16; i++)
#pragma unroll
        for (int r = 0; r < 4; r++) {
          int rl = i * 16 + lq * 4 + r;
          r1s[wave][rl] = s1[i][r];
          r2s[wave][rl] = s2[i][r];
        }
    }
    __syncthreads();
    if (threadIdx.x < MT) {
      int t = threadIdx.x;
      float a = r1s[0][t] + r1s[1][t] + r1s[2][t] + r1s[3][t];
      float b = r2s[0][t] + r2s[1][t] + r2s[2][t] + r2s[3][t];
      float m = a * (1.f / 256.f);
      float var = b * (1.f / 256.f) - m * m;
      mArr[t] = m;
      iArr[t] = rsqrtf(var + 1e-5f);
    }
    __syncthreads();
#pragma unroll
    for (int i = 0; i < MT / 16; i++) {
#pragma unroll
      for (int r = 0; r < 4; r++) {
        int rl = i * 16 + lq * 4 + r;
        int rowg = bm + rl;
        float m = mArr[rl], inv = iArr[rl];
#pragma unroll
        for (int j = 0; j < 4; j++) {
          int cc = bn + j * 16 + lr;
          long idx = (long)rowg * 256 + cc;
          float x = acc[i][j][r] + bv[j] + res[idx];
          float y = (x - m) * inv * lnw[cc] + lnb[cc];
          out_f[idx] = y;
          if (out_b16) out_b16[idx] = f2b(y);
          if (qk_b16)  qk_b16[idx]  = f2b(y + qpos[idx]);
          if (hsp)     hsp[idx]     = y;
        }
      }
    }
  }
}

// ---------------------------------------------------------------------------
// qkv_k: merged Q/K/V projection, MT=32 (grid (128,3) = 384 blocks for full
// CU fill) with direct A loads (no staging drain). y=0 -> Q cols of qkbuf,
// y=1 -> K cols, y=2 -> V (writes vt only).
// ---------------------------------------------------------------------------
__global__ __launch_bounds__(256) void qkv_k(
    const u16* __restrict__ qk_b, const u16* __restrict__ out_b,
    const u16* __restrict__ wsa, const float* __restrict__ bsa,
    u16* __restrict__ qkbuf, u16* __restrict__ vt)
{
  const int sel = blockIdx.y;
  const u16* A = (sel == 2) ? out_b : qk_b;
  const u16* W = wsa + (long)sel * 256 * 256;
  const int wave = threadIdx.x >> 6, lane = threadIdx.x & 63;
  const int bm = blockIdx.x * 32;
  const int bn = wave * 64;
  const int lr = lane & 15, lq = lane >> 4;
  f32x4 acc[2][4] = {};
#pragma unroll
  for (int s = 0; s < 8; s++) {
    short8 af[2], bf[4];
#pragma unroll
    for (int i = 0; i < 2; i++)
      af[i] = *(const short8*)(A + (long)(bm + i * 16 + lr) * 256 + (s * 4 + lq) * 8);
#pragma unroll
    for (int j = 0; j < 4; j++) {
      int cc = bn + j * 16 + lr;
      bf[j] = *(const short8*)(W + (long)cc * 256 + s * 32 + lq * 8);
    }
#pragma unroll
    for (int i = 0; i < 2; i++)
#pragma unroll
      for (int j = 0; j < 4; j++)
        acc[i][j] = __builtin_amdgcn_mfma_f32_16x16x32_bf16(af[i], bf[j], acc[i][j], 0, 0, 0);
  }
  float bv[4];
#pragma unroll
  for (int j = 0; j < 4; j++) bv[j] = bsa[sel * 256 + bn + j * 16 + lr];
#pragma unroll
  for (int j = 0; j < 4; j++) {
    int cc = bn + j * 16 + lr;
#pragma unroll
    for (int i = 0; i < 2; i++) {
#pragma unroll
      for (int r = 0; r < 4; r++) {
        int rr = bm + i * 16 + lq * 4 + r;
        float v = acc[i][j][r] + bv[j];
        if (sel < 2) {
          qkbuf[(long)rr * 512 + sel * 256 + cc] = f2b(v);
        } else {
          int b_ = rr >> 10, q_ = rr & 1023, h_ = cc >> 5, dh_ = cc & 31;
          vt[(long)((((b_ << 3) + h_) << 5) + dh_) * 1024 + q_] = f2b(v);
        }
      }
    }
  }
}

// ---------------------------------------------------------------------------
// Flash self-attention (round-6 proven): block per (b,h,q-tile 128).
// ---------------------------------------------------------------------------
__global__ __launch_bounds__(256) void flash_k(
    const u16* __restrict__ qkbuf, const u16* __restrict__ vt,
    u16* __restrict__ obuf)
{
  const float SC = 0.17677669529663687f;
  __shared__ u16 Plds[4][32][136];
  const int bh = blockIdx.x >> 3;
  const int b = bh >> 3, h = bh & 7;
  const int qt = blockIdx.x & 7;
  const int wave = threadIdx.x >> 6, lane = threadIdx.x & 63;
  const int lr = lane & 15, lq = lane >> 4;
  const int qbase = qt * 128 + wave * 32;

  short8 qf[2];
#pragma unroll
  for (int i = 0; i < 2; i++)
    qf[i] = *(const short8*)(qkbuf + (long)(b * 1024 + qbase + i * 16 + lr) * 512 + h * 32 + lq * 8);

  const u16* Kb = qkbuf + (long)b * 1024 * 512 + 256 + h * 32;
  const u16* Vb = vt + (long)bh * 32 * 1024;

  f32x4 acc_o[2][2] = {};
  float m_run[2][4], l_run[2][4];
#pragma unroll
  for (int i = 0; i < 2; i++)
#pragma unroll
    for (int r = 0; r < 4; r++){ m_run[i][r] = -3e38f; l_run[i][r] = 0.f; }

  for (int kt = 0; kt < 8; kt++) {
    f32x4 s[2][8] = {};
#pragma unroll
    for (int j = 0; j < 8; j++) {
      short8 kf = *(const short8*)(Kb + (long)(kt * 128 + j * 16 + lr) * 512 + lq * 8);
#pragma unroll
      for (int i = 0; i < 2; i++)
        s[i][j] = __builtin_amdgcn_mfma_f32_16x16x32_bf16(qf[i], kf, s[i][j], 0, 0, 0);
    }
#pragma unroll
    for (int i = 0; i < 2; i++) {
#pragma unroll
      for (int r = 0; r < 4; r++) {
        float mx = s[i][0][r];
#pragma unroll
        for (int j = 1; j < 8; j++) mx = fmaxf(mx, s[i][j][r]);
#pragma unroll
        for (int m = 1; m <= 8; m <<= 1) mx = fmaxf(mx, __shfl_xor(mx, m));
        float m_new = fmaxf(m_run[i][r], mx);
        float alpha = __expf((m_run[i][r] - m_new) * SC);
        float sum = 0.f;
        int row = i * 16 + lq * 4 + r;
#pragma unroll
        for (int j = 0; j < 8; j++) {
          float p = __expf((s[i][j][r] - m_new) * SC);
          sum += p;
          Plds[wave][row][j * 16 + lr] = f2b(p);
        }
#pragma unroll
        for (int m = 1; m <= 8; m <<= 1) sum += __shfl_xor(sum, m);
        l_run[i][r] = l_run[i][r] * alpha + sum;
        m_run[i][r] = m_new;
#pragma unroll
        for (int d = 0; d < 2; d++) acc_o[i][d][r] *= alpha;
      }
    }
#pragma unroll
    for (int kc = 0; kc < 4; kc++) {
      short8 pf[2];
#pragma unroll
      for (int i = 0; i < 2; i++)
        pf[i] = *(const short8*)&Plds[wave][i * 16 + lr][kc * 32 + lq * 8];
#pragma unroll
      for (int d = 0; d < 2; d++) {
        short8 vf = *(const short8*)(Vb + (long)(d * 16 + lr) * 1024 + kt * 128 + kc * 32 + lq * 8);
#pragma unroll
        for (int i = 0; i < 2; i++)
          acc_o[i][d] = __builtin_amdgcn_mfma_f32_16x16x32_bf16(pf[i], vf, acc_o[i][d], 0, 0, 0);
      }
    }
  }
#pragma unroll
  for (int i = 0; i < 2; i++) {
#pragma unroll
    for (int r = 0; r < 4; r++) {
      float inv = 1.f / l_run[i][r];
      int q = qbase + i * 16 + lq * 4 + r;
#pragma unroll
      for (int d = 0; d < 2; d++)
        obuf[(long)(b * 1024 + q) * 256 + h * 32 + d * 16 + lr] = f2b(acc_o[i][d][r] * inv);
    }
  }
}

// ---------------------------------------------------------------------------
// gemm64_k (bf16-only): 64x64 block, direct loads. Used for offaw (N=96).
// ---------------------------------------------------------------------------
__global__ __launch_bounds__(256) void gemm64_k(
    const u16* __restrict__ A, int lda,
    const u16* __restrict__ W, int ldw,
    const float* __restrict__ bias,
    float* __restrict__ C, int ldo,
    int M, int N, int K)
{
  const int wave = threadIdx.x >> 6, lane = threadIdx.x & 63;
  const int wm = wave >> 1, wn = wave & 1;
  const int bm = blockIdx.x * 64 + wm * 32;
  const int bn = blockIdx.y * 64 + wn * 32;
  const int lr = lane & 15, lq = lane >> 4;
  const int koff = lq * 8;
  f32x4 acc[2][2] = {};
  const short8 Z8 = {0,0,0,0,0,0,0,0};
  for (int k0 = 0; k0 < K; k0 += 32) {
    short8 af[2], bf[2];
#pragma unroll
    for (int i = 0; i < 2; i++) {
      int r = bm + i * 16 + lr;
      af[i] = (r < M) ? *(const short8*)(A + (long)r * lda + k0 + koff) : Z8;
    }
#pragma unroll
    for (int j = 0; j < 2; j++) {
      int c = bn + j * 16 + lr;
      bf[j] = (c < N) ? *(const short8*)(W + (long)c * ldw + k0 + koff) : Z8;
    }
#pragma unroll
    for (int i = 0; i < 2; i++)
#pragma unroll
      for (int j = 0; j < 2; j++)
        acc[i][j] = __builtin_amdgcn_mfma_f32_16x16x32_bf16(af[i], bf[j], acc[i][j], 0, 0, 0);
  }
#pragma unroll
  for (int j = 0; j < 2; j++) {
    int cc = bn + j * 16 + lr;
    if (cc >= N) continue;
    float bv = bias[cc];
#pragma unroll
    for (int i = 0; i < 2; i++) {
#pragma unroll
      for (int r = 0; r < 4; r++) {
        int rr = bm + i * 16 + lq * 4 + r;
        if (rr >= M) continue;
        C[(long)rr * ldo + cc] = acc[i][j][r] + bv;
      }
    }
  }
}

__global__ __launch_bounds__(256) void init_prep_k(const float* __restrict__ q, const float* __restrict__ qpos,
                                                   float* __restrict__ out_f, u16* __restrict__ out_b,
                                                   u16* __restrict__ qk_b){
  long i = (long)blockIdx.x * 256 + threadIdx.x;
  float o = q[i];
  out_f[i] = o;
  out_b[i] = f2b(o);
  qk_b[i]  = f2b(o + qpos[i]);
}

__global__ __launch_bounds__(256) void msda_k(
    const float* __restrict__ refp,
    const float* __restrict__ off, int ldoff,
    const float* __restrict__ aw, int ldaw,
    const u16* __restrict__ v,
    u16* __restrict__ o,
    long vstride)
{
  int tid = blockIdx.x * 256 + threadIdx.x;
  int dh = tid & 31;
  int h  = (tid >> 5) & 7;
  int bq = tid >> 8;
  int b  = bq >> 10;
  float rx = refp[bq * 2 + 0];
  float ry = refp[bq * 2 + 1];
  const float* offp = off + (long)bq * ldoff + h * 8;
  const float* awp  = aw  + (long)bq * ldaw + h * 4;
  float a0 = awp[0], a1 = awp[1], a2 = awp[2], a3 = awp[3];
  float am = fmaxf(fmaxf(a0, a1), fmaxf(a2, a3));
  float e[4];
  e[0] = __expf(a0 - am); e[1] = __expf(a1 - am); e[2] = __expf(a2 - am); e[3] = __expf(a3 - am);
  float einv = 1.f / (e[0] + e[1] + e[2] + e[3]);
  const u16* vb = v + b * vstride + h * 32 + dh;
  float accv = 0.f;
#pragma unroll
  for (int pp = 0; pp < 4; pp++){
    float x = rx * 150.f + offp[pp * 2 + 0] - 0.5f;
    float y = ry * 200.f + offp[pp * 2 + 1] - 0.5f;
    float x0 = floorf(x), y0 = floorf(y);
    float s = 0.f;
#pragma unroll
    for (int c = 0; c < 4; c++){
      int dx = c & 1, dy = c >> 1;
      float xi = x0 + dx, yi = y0 + dy;
      float wt = (1.f - fabsf(x - xi)) * (1.f - fabsf(y - yi));
      if (xi >= 0.f && xi < 150.f && yi >= 0.f && yi < 200.f && wt > 0.f) {
        int xc = (int)xi, yc = (int)yi;
        s += wt * b2f(vb[((long)yc * 150 + xc) * 256]);
      }
    }
    accv += e[pp] * einv * s;
  }
  o[(long)bq * 256 + h * 32 + dh] = f2b(accv);
}

__global__ __launch_bounds__(256) void refs_k(const float* __restrict__ r, float* __restrict__ dst){
  int i = blockIdx.x * 256 + threadIdx.x;
  dst[i] = r[i & 8191];
}

// ---------------------------------------------------------------------------
extern "C" void kernel_launch(void* const* d_in, const int* in_sizes, int n_in,
                              void* d_out, int out_size, void* d_ws, size_t ws_size,
                              hipStream_t stream)
{
  (void)in_sizes; (void)n_in; (void)out_size;
  const float* query = (const float*)d_in[0];
  const float* qpos  = (const float*)d_in[1];
  const float* refp  = (const float*)d_in[2];
  const float* src   = (const float*)d_in[3];
  const float* sa_in_w  = (const float*)d_in[6];
  const float* sa_in_b  = (const float*)d_in[7];
  const float* sa_out_w = (const float*)d_in[8];
  const float* sa_out_b = (const float*)d_in[9];
  const float* off_w = (const float*)d_in[10];
  const float* off_b = (const float*)d_in[11];
  const float* aw_w  = (const float*)d_in[12];
  const float* aw_b  = (const float*)d_in[13];
  const float* val_w = (const float*)d_in[14];
  const float* val_b = (const float*)d_in[15];
  const float* cout_w = (const float*)d_in[16];
  const float* cout_b = (const float*)d_in[17];
  const float* n1w = (const float*)d_in[18]; const float* n1b = (const float*)d_in[19];
  const float* n2w = (const float*)d_in[20]; const float* n2b = (const float*)d_in[21];
  const float* n3w = (const float*)d_in[22]; const float* n3b = (const float*)d_in[23];
  const float* ff1w = (const float*)d_in[24]; const float* ff1b = (const float*)d_in[25];
  const float* ff2w = (const float*)d_in[26]; const float* ff2b = (const float*)d_in[27];

  float* hs = (float*)d_out;
  float* refs_out = hs + (long)6 * 4096 * 256;

  char* p = (char*)d_ws;
  auto alloc = [&](size_t bytes){ char* r = p; p += (bytes + 255) & ~(size_t)255; return r; };
  float* out_f = (float*)alloc(4194304);
  u16*   qk_b  = (u16*)  alloc(2097152);
  u16*   out_b = (u16*)  alloc(2097152);
  u16* wsa_b  = (u16*)alloc(2359296);
  u16* wsao_b = (u16*)alloc(786432);
  u16* wofaw  = (u16*)alloc(294912);
  u16* wval_b = (u16*)alloc(786432);
  u16* wcao_b = (u16*)alloc(786432);
  u16* wff1_b = (u16*)alloc(3145728);
  u16* wff2_b = (u16*)alloc(3145728);
  float* obc  = (float*)alloc(2304);
  u16* src_b  = (u16*)alloc(61440000);
  u16* qkbuf  = (u16*)alloc(4194304);
  u16* vt     = (u16*)alloc(2097152);
  u16* obuf   = (u16*)alloc(2097152);
  float* oawo = (float*)alloc(1572864);
  u16* mo     = (u16*)alloc(2097152);
  u16* ffh    = (u16*)alloc(8388608);
  size_t used = (size_t)(p - (char*)d_ws);
  const bool big = (ws_size >= used + 368640000ull);   // room for 6-layer vsrc
  u16* vsrc = (u16*)alloc(big ? 368640000ull : 61440000ull);

  init_prep_k<<<4096, 256, 0, stream>>>(query, qpos, out_f, out_b, qk_b);
  cvtall_k<<<17761, 256, 0, stream>>>(sa_in_w, sa_out_w, val_w, cout_w, ff1w, ff2w,
                                      off_w, aw_w, off_b, aw_b, src,
                                      wsa_b, wsao_b, wval_b, wcao_b, wff1_b, wff2_b,
                                      wofaw, obc, src_b);
  if (big) {
    vproj6_k<<<1875, 256, 0, stream>>>(src_b, wval_b, val_b, vsrc);
  }

  for (int l = 0; l < 6; l++){
    const u16* wsa = wsa_b + (long)l * 768 * 256;
    // ---- self attention (flash) ----
    qkv_k<<<dim3(128,3,1),256,0,stream>>>(qk_b, out_b, wsa, sa_in_b + l * 768, qkbuf, vt);
    flash_k<<<256,256,0,stream>>>(qkbuf, vt, obuf);
    gemm_w_k<16,false,false,false,true><<<dim3(256,1,1),256,0,stream>>>(   // out-proj + norm2
        obuf, 256, wsao_b + (long)l*65536, 0, sa_out_b + l*256, 0, nullptr, 0, 0, 256,
        nullptr, out_f, n2w + l*256, n2b + l*256, qpos, out_f, nullptr, qk_b, nullptr);
    // ---- deformable cross attention ----
    gemm64_k<<<dim3(64,2,1),256,0,stream>>>(qk_b, 256, wofaw + (long)l*24576, 256,
        obc + l*96, oawo, 96, 4096, 96, 256);
    if (!big) {
      gemm_w_k<64,false,true,false,false><<<dim3(1875,1,1),256,0,stream>>>(
          src_b, 256, wval_b + (long)l*65536, 0, val_b + l*256, 0, vsrc, 256, 0, 256,
          nullptr, nullptr,nullptr,nullptr,nullptr,nullptr,nullptr,nullptr,nullptr);
    }
    const u16* vsl = big ? (vsrc + (long)l*30720000) : vsrc;
    msda_k<<<4096,256,0,stream>>>(refp, oawo, 96, oawo + 64, 96, vsl, mo, 7680000);
    gemm_w_k<16,false,false,false,true><<<dim3(256,1,1),256,0,stream>>>(   // ca-out + norm1
        mo, 256, wcao_b + (long)l*65536, 0, cout_b + l*256, 0, nullptr, 0, 0, 256,
        nullptr, out_f, n1w + l*256, n1b + l*256, nullptr, out_f, out_b, nullptr, nullptr);
    // ---- ffn ----
    gemm_w_k<64,true,true,false,false><<<dim3(64,4,1),256,0,stream>>>(     // ff1 + relu
        out_b, 256, wff1_b + (long)l*262144, 0, ff1b + l*1024, 0, ffh, 1024, 0, 256,
        nullptr, nullptr,nullptr,nullptr,nullptr,nullptr,nullptr,nullptr,nullptr);
    gemm_w_k<16,false,false,false,true><<<dim3(256,1,1),256,0,stream>>>(   // ff2 + norm3
        ffh, 1024, wff2_b + (long)l*262144, 0, ff2b + l*256, 0, nullptr, 0, 0, 1024,
        nullptr, out_f, n3w + l*256, n3b + l*256, qpos, out_f, out_b, qk_b,
        hs + (long)l*1048576);
  }
  refs_k<<<192,256,0,stream>>>(refp, refs_out);
}

// Round 10
// 1557.338 us; speedup vs baseline: 1.5847x; 1.0064x over previous
//
#include <hip/hip_runtime.h>

typedef __attribute__((ext_vector_type(8))) short short8;
typedef __attribute__((ext_vector_type(4))) float f32x4;
typedef unsigned short u16;

#define DEVI static __device__ __forceinline__

// BS=4 NQ=1024 D=256 NH=8 NP=4 L=6 DFF=1024 H=200 W=150 NV=30000 DH=32
// d_in/d_out are FP32. Internals: bf16 MFMA, fp32 accum, fp32 residual+LN.
DEVI float b2f(u16 u){ unsigned int x = ((unsigned int)u) << 16; float f; __builtin_memcpy(&f, &x, 4); return f; }
DEVI u16 f2b(float f){ unsigned int u; __builtin_memcpy(&u, &f, 4); u += 0x7fffu + ((u >> 16) & 1u); return (u16)(u >> 16); }
DEVI short8 cvt8(const float* __restrict__ p){
  f32x4 a = *(const f32x4*)p;
  f32x4 b = *(const f32x4*)(p + 4);
  short8 r;
  r[0]=(short)f2b(a[0]); r[1]=(short)f2b(a[1]); r[2]=(short)f2b(a[2]); r[3]=(short)f2b(a[3]);
  r[4]=(short)f2b(b[0]); r[5]=(short)f2b(b[1]); r[6]=(short)f2b(b[2]); r[7]=(short)f2b(b[3]);
  return r;
}

// ---------------------------------------------------------------------------
// One-shot convert/pack of ALL fp32 params -> bf16 (plus obc fp32 pack).
// ---------------------------------------------------------------------------
__global__ __launch_bounds__(256) void cvtall_k(
    const float* __restrict__ sa_in_w, const float* __restrict__ sa_out_w,
    const float* __restrict__ val_w,   const float* __restrict__ cout_w,
    const float* __restrict__ ff1w,    const float* __restrict__ ff2w,
    const float* __restrict__ off_w,   const float* __restrict__ aw_w,
    const float* __restrict__ off_b,   const float* __restrict__ aw_b,
    const float* __restrict__ src,
    u16* __restrict__ wsa_b, u16* __restrict__ wsao_b, u16* __restrict__ wval_b,
    u16* __restrict__ wcao_b, u16* __restrict__ wff1_b, u16* __restrict__ wff2_b,
    u16* __restrict__ wofaw, float* __restrict__ obc, u16* __restrict__ src_b)
{
  long u = (long)blockIdx.x * 256 + threadIdx.x;
  if (u < 147456) { ((short8*)wsa_b)[u]  = cvt8(sa_in_w  + u * 8); return; } u -= 147456;
  if (u < 49152)  { ((short8*)wsao_b)[u] = cvt8(sa_out_w + u * 8); return; } u -= 49152;
  if (u < 49152)  { ((short8*)wval_b)[u] = cvt8(val_w    + u * 8); return; } u -= 49152;
  if (u < 49152)  { ((short8*)wcao_b)[u] = cvt8(cout_w   + u * 8); return; } u -= 49152;
  if (u < 196608) { ((short8*)wff1_b)[u] = cvt8(ff1w     + u * 8); return; } u -= 196608;
  if (u < 196608) { ((short8*)wff2_b)[u] = cvt8(ff2w     + u * 8); return; } u -= 196608;
  if (u < 12288)  { long e = u * 8; int l = (int)(e >> 14); long rem = e & 16383;
                    ((short8*)wofaw)[(l * 24576 + rem) >> 3] = cvt8(off_w + e); return; } u -= 12288;
  if (u < 6144)   { long e = u * 8; int l = (int)(e >> 13); long rem = e & 8191;
                    ((short8*)wofaw)[(l * 24576 + 16384 + rem) >> 3] = cvt8(aw_w + e); return; } u -= 6144;
  if (u < 3840000){ ((short8*)src_b)[u]  = cvt8(src + u * 8); return; } u -= 3840000;
  if (u < 72) {
    long e0 = u * 8;
#pragma unroll
    for (int j = 0; j < 8; j++) {
      long e = e0 + j;
      if (e < 384) { int l = (int)(e >> 6); obc[l * 96 + (e & 63)] = off_b[e]; }
      else { long e2 = e - 384; int l = (int)(e2 >> 5); obc[l * 96 + 64 + (e2 & 31)] = aw_b[e2]; }
    }
  }
}

// ---------------------------------------------------------------------------
// vproj6_k (round-7 proven, ~251us, traffic-exact): value projection for ALL
// 6 layers, layer loop inside the block. As staged once; 8KB chunked Cs
// transposed epilogue (full-line stores). Spill rules: no min-waves bound;
// all accumulator indices compile-time constant.
// ---------------------------------------------------------------------------
__global__ __launch_bounds__(256) void vproj6_k(
    const u16* __restrict__ A,       // src_b, lda = 256
    const u16* __restrict__ W,       // wval_b, 65536 elems per layer
    const float* __restrict__ bias,  // val_b, 256 per layer
    u16* __restrict__ C)             // vsrc, 30720000 elems per layer
{
  __shared__ u16 As[64 * 256];
  __shared__ u16 Cs[16 * 256];
  const int wave = threadIdx.x >> 6, lane = threadIdx.x & 63;
  const int bm = blockIdx.x * 64;
  const int bn = wave * 64;
  const int lr = lane & 15, lq = lane >> 4;
#pragma unroll
  for (int it = 0; it < 8; it++) {
    int ub = wave * 512 + it * 64;
    int u = ub + lane;
    int row = u & 63, kgrp = u >> 6;
    const u16* ga = A + (long)(bm + row) * 256 + kgrp * 8;
    __builtin_amdgcn_global_load_lds(
        (const __attribute__((address_space(1))) void*)ga,
        (__attribute__((address_space(3))) void*)(As + ub * 8), 16, 0, 0);
  }
  __syncthreads();
#pragma unroll 1
  for (int l = 0; l < 6; l++) {
    const u16* Wz = W + (long)l * 65536;
    f32x4 acc[4][4] = {};
#pragma unroll
    for (int s = 0; s < 8; s++) {
      short8 af[4], bf[4];
#pragma unroll
      for (int i = 0; i < 4; i++)
        af[i] = *(const short8*)(As + ((s * 4 + lq) * 64 + i * 16 + lr) * 8);
#pragma unroll
      for (int j = 0; j < 4; j++)
        bf[j] = *(const short8*)(Wz + (long)(bn + j * 16 + lr) * 256 + s * 32 + lq * 8);
#pragma unroll
      for (int i = 0; i < 4; i++)
#pragma unroll
        for (int j = 0; j < 4; j++)
          acc[i][j] = __builtin_amdgcn_mfma_f32_16x16x32_bf16(af[i], bf[j], acc[i][j], 0, 0, 0);
    }
    const float* bz = bias + l * 256;
    u16* Cl = C + (long)l * 30720000 + (long)bm * 256;
#pragma unroll
    for (int i = 0; i < 4; i++) {
      __syncthreads();
#pragma unroll
      for (int j = 0; j < 4; j++) {
        int colt = bn + j * 16 + lr;
        float bv = bz[colt];
#pragma unroll
        for (int r = 0; r < 4; r++) {
          int rowl = lq * 4 + r;
          int byte = (rowl << 9) + (colt << 1);
          byte ^= ((rowl >> 2) & 3) << 5;
          *(u16*)((char*)Cs + byte) = f2b(acc[i][j][r] + bv);
        }
      }
      __syncthreads();
#pragma unroll
      for (int t = 0; t < 2; t++) {
        int idx = t * 256 + threadIdx.x;
        int byte = idx << 4;
        byte ^= ((byte >> 11) & 3) << 5;
        short8 v = *(const short8*)((const char*)Cs + byte);
        ((short8*)(Cl + (long)i * 4096))[idx] = v;
      }
    }
  }
}

// ---------------------------------------------------------------------------
// gemm_w_k<MT,...,XTRA>: MT(M) x 256(N) block; direct A loads (round-8: no
// staging drain at K=256). LN epilogue optional. XTRA fuses a dependent
// consumer GEMM reading this block's y-tile from LDS (block covers all 256
// cols of its rows, so the consumer's K=256 input is block-local):
//   XTRA=1: offaw — qkS=f2b(y+qpos), N=96 (3 waves x 2 tiles) -> fp32 xout
//   XTRA=2: ff1   — yS=f2b(y), N=1024 (4 waves x 16 tiles, 2 passes of 8,
//           relu) -> bf16 xout.  [r9 bug: only 4 tiles/wave were computed]
// yS padded to 264 u16/row (row stride 132 dwords -> <=2-way conflicts).
// All accumulator indices compile-time constant (r6 spill rule).
// ---------------------------------------------------------------------------
template<int MT, bool RELU, bool OUTBF, bool VT, bool LN, int XTRA>
__global__ __launch_bounds__(256) void gemm_w_k(
    const u16* __restrict__ A, int lda,
    const u16* __restrict__ W, long wZ,
    const float* __restrict__ bias, int bZ,
    void* __restrict__ Cv, int ldo, long cZ,
    int K,
    u16* __restrict__ vt,
    const float* __restrict__ res,
    const float* __restrict__ lnw, const float* __restrict__ lnb,
    const float* __restrict__ qpos,
    float* __restrict__ out_f, u16* __restrict__ out_b16,
    u16* __restrict__ qk_b16, float* __restrict__ hsp,
    const u16* __restrict__ xw, const float* __restrict__ xb,
    void* __restrict__ xout)
{
  __shared__ float r1s[4][64], r2s[4][64], mArr[64], iArr[64];
  __shared__ u16 yS[(XTRA > 0) ? 16 : 1][264];
  const int wave = threadIdx.x >> 6, lane = threadIdx.x & 63;
  const int bm = blockIdx.x * MT;
  const int bn = blockIdx.y * 256 + wave * 64;
  const int lr = lane & 15, lq = lane >> 4;
  const u16* Wz = W + (long)blockIdx.z * wZ;
  const float* bz = bias + (long)blockIdx.z * bZ;
  f32x4 acc[MT / 16][4] = {};
  const int nchunks = K >> 8;
  for (int ch = 0; ch < nchunks; ch++) {
#pragma unroll
    for (int s = 0; s < 8; s++) {
      short8 af[MT / 16], bf[4];
#pragma unroll
      for (int i = 0; i < MT / 16; i++)
        af[i] = *(const short8*)(A + (long)(bm + i * 16 + lr) * lda + ch * 256 + (s * 4 + lq) * 8);
#pragma unroll
      for (int j = 0; j < 4; j++) {
        int cc = bn + j * 16 + lr;
        bf[j] = *(const short8*)(Wz + (long)cc * K + ch * 256 + s * 32 + lq * 8);
      }
#pragma unroll
      for (int i = 0; i < MT / 16; i++)
#pragma unroll
        for (int j = 0; j < 4; j++)
          acc[i][j] = __builtin_amdgcn_mfma_f32_16x16x32_bf16(af[i], bf[j], acc[i][j], 0, 0, 0);
    }
  }

  float bv[4];
#pragma unroll
  for (int j = 0; j < 4; j++) bv[j] = bz[bn + j * 16 + lr];

  if (!LN) {
    char* Cz = (char*)Cv;
#pragma unroll
    for (int j = 0; j < 4; j++) {
      int cc = bn + j * 16 + lr;
#pragma unroll
      for (int i = 0; i < MT / 16; i++) {
#pragma unroll
        for (int r = 0; r < 4; r++) {
          int rr = bm + i * 16 + lq * 4 + r;
          float v = acc[i][j][r] + bv[j];
          if (RELU) v = fmaxf(v, 0.f);
          long idx = (long)blockIdx.z * cZ + (long)rr * ldo + cc;
          if (OUTBF) ((u16*)Cz)[idx] = f2b(v);
          else       ((float*)Cz)[idx] = v;
          if (VT) {
            int b_ = rr >> 10, q_ = rr & 1023, h_ = cc >> 5, dh_ = cc & 31;
            vt[(long)((((b_ << 3) + h_) << 5) + dh_) * 1024 + q_] = f2b(v);
          }
        }
      }
    }
  } else {
    float s1[MT / 16][4] = {}, s2[MT / 16][4] = {};
#pragma unroll
    for (int i = 0; i < MT / 16; i++) {
#pragma unroll
      for (int r = 0; r < 4; r++) {
        int rowg = bm + i * 16 + lq * 4 + r;
#pragma unroll
        for (int j = 0; j < 4; j++) {
          int cc = bn + j * 16 + lr;
          float x = acc[i][j][r] + bv[j] + res[(long)rowg * 256 + cc];
          s1[i][r] += x; s2[i][r] += x * x;
        }
      }
    }
#pragma unroll
    for (int i = 0; i < MT / 16; i++)
#pragma unroll
      for (int r = 0; r < 4; r++) {
#pragma unroll
        for (int m = 1; m <= 8; m <<= 1) {
          s1[i][r] += __shfl_xor(s1[i][r], m);
          s2[i][r] += __shfl_xor(s2[i][r], m);
        }
      }
    if (lr == 0) {
#pragma unroll
      for (int i = 0; i < MT / 16; i++)
#pragma unroll
        for (int r = 0; r < 4; r++) {
          int rl = i * 16 + lq * 4 + r;
          r1s[wave][rl] = s1[i][r];
          r2s[wave][rl] = s2[i][r];
        }
    }
    __syncthreads();
    if (threadIdx.x < MT) {
      int t = threadIdx.x;
      float a = r1s[0][t] + r1s[1][t] + r1s[2][t] + r1s[3][t];
      float b = r2s[0][t] + r2s[1][t] + r2s[2][t] + r2s[3][t];
      float m = a * (1.f / 256.f);
      float var = b * (1.f / 256.f) - m * m;
      mArr[t] = m;
      iArr[t] = rsqrtf(var + 1e-5f);
    }
    __syncthreads();
#pragma unroll
    for (int i = 0; i < MT / 16; i++) {
#pragma unroll
      for (int r = 0; r < 4; r++) {
        int rl = i * 16 + lq * 4 + r;
        int rowg = bm + rl;
        float m = mArr[rl], inv = iArr[rl];
#pragma unroll
        for (int j = 0; j < 4; j++) {
          int cc = bn + j * 16 + lr;
          long idx = (long)rowg * 256 + cc;
          float x = acc[i][j][r] + bv[j] + res[idx];
          float y = (x - m) * inv * lnw[cc] + lnb[cc];
          out_f[idx] = y;
          if (out_b16) out_b16[idx] = f2b(y);
          if (qk_b16)  qk_b16[idx]  = f2b(y + qpos[idx]);
          if (hsp)     hsp[idx]     = y;
          if (XTRA == 1) yS[rl][cc] = f2b(y + qpos[idx]);
          if (XTRA == 2) yS[rl][cc] = f2b(y);
        }
      }
    }
    if (XTRA > 0) {
      __syncthreads();
      if (XTRA == 1) {
        // offaw: 6 col-tiles of 16 over N=96; waves 0..2 take 2 tiles each
        if (wave < 3) {
          f32x4 a2[2] = {};
#pragma unroll
          for (int s = 0; s < 8; s++) {
            short8 af2 = *(const short8*)&yS[lr][(s * 4 + lq) * 8];
#pragma unroll
            for (int t = 0; t < 2; t++) {
              int cc2 = (wave * 2 + t) * 16 + lr;
              short8 bf2 = *(const short8*)(xw + (long)cc2 * 256 + s * 32 + lq * 8);
              a2[t] = __builtin_amdgcn_mfma_f32_16x16x32_bf16(af2, bf2, a2[t], 0, 0, 0);
            }
          }
          float* xo = (float*)xout;
#pragma unroll
          for (int t = 0; t < 2; t++) {
            int cc2 = (wave * 2 + t) * 16 + lr;
            float bv2 = xb[cc2];
#pragma unroll
            for (int r = 0; r < 4; r++)
              xo[(long)(bm + lq * 4 + r) * 96 + cc2] = a2[t][r] + bv2;
          }
        }
      } else {
        // ff1: wave covers cols wave*256..+255 = 16 col-tiles of 16, relu,
        // bf16 out. Two statically-unrolled passes of 8 accumulators (VGPR).
        u16* xo = (u16*)xout;
#pragma unroll
        for (int hh = 0; hh < 2; hh++) {
          f32x4 a2[8] = {};
#pragma unroll
          for (int s = 0; s < 8; s++) {
            short8 af2 = *(const short8*)&yS[lr][(s * 4 + lq) * 8];
#pragma unroll
            for (int j = 0; j < 8; j++) {
              int cc2 = wave * 256 + (hh * 8 + j) * 16 + lr;
              short8 bf2 = *(const short8*)(xw + (long)cc2 * 256 + s * 32 + lq * 8);
              a2[j] = __builtin_amdgcn_mfma_f32_16x16x32_bf16(af2, bf2, a2[j], 0, 0, 0);
            }
          }
#pragma unroll
          for (int j = 0; j < 8; j++) {
            int cc2 = wave * 256 + (hh * 8 + j) * 16 + lr;
            float bv2 = xb[cc2];
#pragma unroll
            for (int r = 0; r < 4; r++) {
              float v = fmaxf(a2[j][r] + bv2, 0.f);
              xo[(long)(bm + lq * 4 + r) * 1024 + cc2] = f2b(v);
            }
          }
        }
      }
    }
  }
}

// ---------------------------------------------------------------------------
// qkv_k: merged Q/K/V projection, MT=32, grid (128,3), direct A loads.
// ---------------------------------------------------------------------------
__global__ __launch_bounds__(256) void qkv_k(
    const u16* __restrict__ qk_b, const u16* __restrict__ out_b,
    const u16* __restrict__ wsa, const float* __restrict__ bsa,
    u16* __restrict__ qkbuf, u16* __restrict__ vt)
{
  const int sel = blockIdx.y;
  const u16* A = (sel == 2) ? out_b : qk_b;
  const u16* W = wsa + (long)sel * 256 * 256;
  const int wave = threadIdx.x >> 6, lane = threadIdx.x & 63;
  const int bm = blockIdx.x * 32;
  const int bn = wave * 64;
  const int lr = lane & 15, lq = lane >> 4;
  f32x4 acc[2][4] = {};
#pragma unroll
  for (int s = 0; s < 8; s++) {
    short8 af[2], bf[4];
#pragma unroll
    for (int i = 0; i < 2; i++)
      af[i] = *(const short8*)(A + (long)(bm + i * 16 + lr) * 256 + (s * 4 + lq) * 8);
#pragma unroll
    for (int j = 0; j < 4; j++) {
      int cc = bn + j * 16 + lr;
      bf[j] = *(const short8*)(W + (long)cc * 256 + s * 32 + lq * 8);
    }
#pragma unroll
    for (int i = 0; i < 2; i++)
#pragma unroll
      for (int j = 0; j < 4; j++)
        acc[i][j] = __builtin_amdgcn_mfma_f32_16x16x32_bf16(af[i], bf[j], acc[i][j], 0, 0, 0);
  }
  float bv[4];
#pragma unroll
  for (int j = 0; j < 4; j++) bv[j] = bsa[sel * 256 + bn + j * 16 + lr];
#pragma unroll
  for (int j = 0; j < 4; j++) {
    int cc = bn + j * 16 + lr;
#pragma unroll
    for (int i = 0; i < 2; i++) {
#pragma unroll
      for (int r = 0; r < 4; r++) {
        int rr = bm + i * 16 + lq * 4 + r;
        float v = acc[i][j][r] + bv[j];
        if (sel < 2) {
          qkbuf[(long)rr * 512 + sel * 256 + cc] = f2b(v);
        } else {
          int b_ = rr >> 10, q_ = rr & 1023, h_ = cc >> 5, dh_ = cc & 31;
          vt[(long)((((b_ << 3) + h_) << 5) + dh_) * 1024 + q_] = f2b(v);
        }
      }
    }
  }
}

// ---------------------------------------------------------------------------
// Flash self-attention: block per (b,h,q-tile 64); 16 q-rows per wave.
// Round-9: q-tile halved (128->64) -> grid 512 (was 256 = 1 wave/SIMD, zero
// TLP; now 2 blocks/CU so dependency stalls in QK/softmax/PV overlap).
// ---------------------------------------------------------------------------
__global__ __launch_bounds__(256) void flash_k(
    const u16* __restrict__ qkbuf, const u16* __restrict__ vt,
    u16* __restrict__ obuf)
{
  const float SC = 0.17677669529663687f;
  __shared__ u16 Plds[4][16][136];
  const int bh = blockIdx.x >> 4;
  const int b = bh >> 3, h = bh & 7;
  const int qt = blockIdx.x & 15;
  const int wave = threadIdx.x >> 6, lane = threadIdx.x & 63;
  const int lr = lane & 15, lq = lane >> 4;
  const int qbase = qt * 64 + wave * 16;

  short8 qf = *(const short8*)(qkbuf + (long)(b * 1024 + qbase + lr) * 512 + h * 32 + lq * 8);

  const u16* Kb = qkbuf + (long)b * 1024 * 512 + 256 + h * 32;
  const u16* Vb = vt + (long)bh * 32 * 1024;

  f32x4 acc_o[2] = {};
  float m_run[4], l_run[4];
#pragma unroll
  for (int r = 0; r < 4; r++){ m_run[r] = -3e38f; l_run[r] = 0.f; }

  for (int kt = 0; kt < 8; kt++) {
    f32x4 s[8] = {};
#pragma unroll
    for (int j = 0; j < 8; j++) {
      short8 kf = *(const short8*)(Kb + (long)(kt * 128 + j * 16 + lr) * 512 + lq * 8);
      s[j] = __builtin_amdgcn_mfma_f32_16x16x32_bf16(qf, kf, s[j], 0, 0, 0);
    }
#pragma unroll
    for (int r = 0; r < 4; r++) {
      float mx = s[0][r];
#pragma unroll
      for (int j = 1; j < 8; j++) mx = fmaxf(mx, s[j][r]);
#pragma unroll
      for (int m = 1; m <= 8; m <<= 1) mx = fmaxf(mx, __shfl_xor(mx, m));
      float m_new = fmaxf(m_run[r], mx);
      float alpha = __expf((m_run[r] - m_new) * SC);
      float sum = 0.f;
      int row = lq * 4 + r;
#pragma unroll
      for (int j = 0; j < 8; j++) {
        float p = __expf((s[j][r] - m_new) * SC);
        sum += p;
        Plds[wave][row][j * 16 + lr] = f2b(p);
      }
#pragma unroll
      for (int m = 1; m <= 8; m <<= 1) sum += __shfl_xor(sum, m);
      l_run[r] = l_run[r] * alpha + sum;
      m_run[r] = m_new;
#pragma unroll
      for (int d = 0; d < 2; d++) acc_o[d][r] *= alpha;
    }
#pragma unroll
    for (int kc = 0; kc < 4; kc++) {
      short8 pf = *(const short8*)&Plds[wave][lr][kc * 32 + lq * 8];
#pragma unroll
      for (int d = 0; d < 2; d++) {
        short8 vf = *(const short8*)(Vb + (long)(d * 16 + lr) * 1024 + kt * 128 + kc * 32 + lq * 8);
        acc_o[d] = __builtin_amdgcn_mfma_f32_16x16x32_bf16(pf, vf, acc_o[d], 0, 0, 0);
      }
    }
  }
#pragma unroll
  for (int r = 0; r < 4; r++) {
    float inv = 1.f / l_run[r];
    int q = qbase + lq * 4 + r;
#pragma unroll
    for (int d = 0; d < 2; d++)
      obuf[(long)(b * 1024 + q) * 256 + h * 32 + d * 16 + lr] = f2b(acc_o[d][r] * inv);
  }
}

__global__ __launch_bounds__(256) void init_prep_k(const float* __restrict__ q, const float* __restrict__ qpos,
                                                   float* __restrict__ out_f, u16* __restrict__ out_b,
                                                   u16* __restrict__ qk_b){
  long i = (long)blockIdx.x * 256 + threadIdx.x;
  float o = q[i];
  out_f[i] = o;
  out_b[i] = f2b(o);
  qk_b[i]  = f2b(o + qpos[i]);
}

__global__ __launch_bounds__(256) void msda_k(
    const float* __restrict__ refp,
    const float* __restrict__ off, int ldoff,
    const float* __restrict__ aw, int ldaw,
    const u16* __restrict__ v,
    u16* __restrict__ o,
    long vstride)
{
  int tid = blockIdx.x * 256 + threadIdx.x;
  int dh = tid & 31;
  int h  = (tid >> 5) & 7;
  int bq = tid >> 8;
  int b  = bq >> 10;
  float rx = refp[bq * 2 + 0];
  float ry = refp[bq * 2 + 1];
  const float* offp = off + (long)bq * ldoff + h * 8;
  const float* awp  = aw  + (long)bq * ldaw + h * 4;
  float a0 = awp[0], a1 = awp[1], a2 = awp[2], a3 = awp[3];
  float am = fmaxf(fmaxf(a0, a1), fmaxf(a2, a3));
  float e[4];
  e[0] = __expf(a0 - am); e[1] = __expf(a1 - am); e[2] = __expf(a2 - am); e[3] = __expf(a3 - am);
  float einv = 1.f / (e[0] + e[1] + e[2] + e[3]);
  const u16* vb = v + b * vstride + h * 32 + dh;
  float accv = 0.f;
#pragma unroll
  for (int pp = 0; pp < 4; pp++){
    float x = rx * 150.f + offp[pp * 2 + 0] - 0.5f;
    float y = ry * 200.f + offp[pp * 2 + 1] - 0.5f;
    float x0 = floorf(x), y0 = floorf(y);
    float s = 0.f;
#pragma unroll
    for (int c = 0; c < 4; c++){
      int dx = c & 1, dy = c >> 1;
      float xi = x0 + dx, yi = y0 + dy;
      float wt = (1.f - fabsf(x - xi)) * (1.f - fabsf(y - yi));
      if (xi >= 0.f && xi < 150.f && yi >= 0.f && yi < 200.f && wt > 0.f) {
        int xc = (int)xi, yc = (int)yi;
        s += wt * b2f(vb[((long)yc * 150 + xc) * 256]);
      }
    }
    accv += e[pp] * einv * s;
  }
  o[(long)bq * 256 + h * 32 + dh] = f2b(accv);
}

__global__ __launch_bounds__(256) void refs_k(const float* __restrict__ r, float* __restrict__ dst){
  int i = blockIdx.x * 256 + threadIdx.x;
  dst[i] = r[i & 8191];
}

// ---------------------------------------------------------------------------
extern "C" void kernel_launch(void* const* d_in, const int* in_sizes, int n_in,
                              void* d_out, int out_size, void* d_ws, size_t ws_size,
                              hipStream_t stream)
{
  (void)in_sizes; (void)n_in; (void)out_size;
  const float* query = (const float*)d_in[0];
  const float* qpos  = (const float*)d_in[1];
  const float* refp  = (const float*)d_in[2];
  const float* src   = (const float*)d_in[3];
  const float* sa_in_w  = (const float*)d_in[6];
  const float* sa_in_b  = (const float*)d_in[7];
  const float* sa_out_w = (const float*)d_in[8];
  const float* sa_out_b = (const float*)d_in[9];
  const float* off_w = (const float*)d_in[10];
  const float* off_b = (const float*)d_in[11];
  const float* aw_w  = (const float*)d_in[12];
  const float* aw_b  = (const float*)d_in[13];
  const float* val_w = (const float*)d_in[14];
  const float* val_b = (const float*)d_in[15];
  const float* cout_w = (const float*)d_in[16];
  const float* cout_b = (const float*)d_in[17];
  const float* n1w = (const float*)d_in[18]; const float* n1b = (const float*)d_in[19];
  const float* n2w = (const float*)d_in[20]; const float* n2b = (const float*)d_in[21];
  const float* n3w = (const float*)d_in[22]; const float* n3b = (const float*)d_in[23];
  const float* ff1w = (const float*)d_in[24]; const float* ff1b = (const float*)d_in[25];
  const float* ff2w = (const float*)d_in[26]; const float* ff2b = (const float*)d_in[27];

  float* hs = (float*)d_out;
  float* refs_out = hs + (long)6 * 4096 * 256;

  char* p = (char*)d_ws;
  auto alloc = [&](size_t bytes){ char* r = p; p += (bytes + 255) & ~(size_t)255; return r; };
  float* out_f = (float*)alloc(4194304);
  u16*   qk_b  = (u16*)  alloc(2097152);
  u16*   out_b = (u16*)  alloc(2097152);
  u16* wsa_b  = (u16*)alloc(2359296);
  u16* wsao_b = (u16*)alloc(786432);
  u16* wofaw  = (u16*)alloc(294912);
  u16* wval_b = (u16*)alloc(786432);
  u16* wcao_b = (u16*)alloc(786432);
  u16* wff1_b = (u16*)alloc(3145728);
  u16* wff2_b = (u16*)alloc(3145728);
  float* obc  = (float*)alloc(2304);
  u16* src_b  = (u16*)alloc(61440000);
  u16* qkbuf  = (u16*)alloc(4194304);
  u16* vt     = (u16*)alloc(2097152);
  u16* obuf   = (u16*)alloc(2097152);
  float* oawo = (float*)alloc(1572864);
  u16* mo     = (u16*)alloc(2097152);
  u16* ffh    = (u16*)alloc(8388608);
  size_t used = (size_t)(p - (char*)d_ws);
  const bool big = (ws_size >= used + 368640000ull);   // room for 6-layer vsrc
  u16* vsrc = (u16*)alloc(big ? 368640000ull : 61440000ull);

  init_prep_k<<<4096, 256, 0, stream>>>(query, qpos, out_f, out_b, qk_b);
  cvtall_k<<<17761, 256, 0, stream>>>(sa_in_w, sa_out_w, val_w, cout_w, ff1w, ff2w,
                                      off_w, aw_w, off_b, aw_b, src,
                                      wsa_b, wsao_b, wval_b, wcao_b, wff1_b, wff2_b,
                                      wofaw, obc, src_b);
  if (big) {
    vproj6_k<<<1875, 256, 0, stream>>>(src_b, wval_b, val_b, vsrc);
  }

  for (int l = 0; l < 6; l++){
    const u16* wsa = wsa_b + (long)l * 768 * 256;
    // ---- self attention (flash) ----
    qkv_k<<<dim3(128,3,1),256,0,stream>>>(qk_b, out_b, wsa, sa_in_b + l * 768, qkbuf, vt);
    flash_k<<<512,256,0,stream>>>(qkbuf, vt, obuf);
    // out-proj + norm2 + FUSED offaw (qk staged in LDS; gemm64 launch removed)
    gemm_w_k<16,false,false,false,true,1><<<dim3(256,1,1),256,0,stream>>>(
        obuf, 256, wsao_b + (long)l*65536, 0, sa_out_b + l*256, 0, nullptr, 0, 0, 256,
        nullptr, out_f, n2w + l*256, n2b + l*256, qpos, out_f, nullptr, nullptr, nullptr,
        wofaw + (long)l*24576, obc + l*96, oawo);
    // ---- deformable cross attention ----
    if (!big) {
      gemm_w_k<64,false,true,false,false,0><<<dim3(1875,1,1),256,0,stream>>>(
          src_b, 256, wval_b + (long)l*65536, 0, val_b + l*256, 0, vsrc, 256, 0, 256,
          nullptr, nullptr,nullptr,nullptr,nullptr,nullptr,nullptr,nullptr,nullptr,
          nullptr, nullptr, nullptr);
    }
    const u16* vsl = big ? (vsrc + (long)l*30720000) : vsrc;
    msda_k<<<4096,256,0,stream>>>(refp, oawo, 96, oawo + 64, 96, vsl, mo, 7680000);
    // ca-out + norm1 + FUSED ff1 (y staged in LDS; ff1 launch removed)
    gemm_w_k<16,false,false,false,true,2><<<dim3(256,1,1),256,0,stream>>>(
        mo, 256, wcao_b + (long)l*65536, 0, cout_b + l*256, 0, nullptr, 0, 0, 256,
        nullptr, out_f, n1w + l*256, n1b + l*256, nullptr, out_f, nullptr, nullptr, nullptr,
        wff1_b + (long)l*262144, ff1b + l*1024, ffh);
    // ---- ffn tail ----
    gemm_w_k<16,false,false,false,true,0><<<dim3(256,1,1),256,0,stream>>>(   // ff2 + norm3
        ffh, 1024, wff2_b + (long)l*262144, 0, ff2b + l*256, 0, nullptr, 0, 0, 1024,
        nullptr, out_f, n3w + l*256, n3b + l*256, qpos, out_f, out_b, qk_b,
        hs + (long)l*1048576, nullptr, nullptr, nullptr);
  }
  refs_k<<<192,256,0,stream>>>(refp, refs_out);
}